// Round 1
// baseline (809.032 us; speedup 1.0000x reference)
//
#include <hip/hip_runtime.h>

#define BSZ 16384
#define DD  768
#define KK  4
#define NH1 512
#define NH2 256

// ---------------------------------------------------------------------------
// k1: h1 = relu(LN(emb @ W1 + b1))   emb (B,768)  W1 (768,512)  h1 (B,512)
// block: 256 threads, 16 rows. Each thread: cols {t, t+256}, 16 rows.
__global__ __launch_bounds__(256) void k_gemm_ln1(
    const float* __restrict__ emb, const float* __restrict__ W1,
    const float* __restrict__ b1, const float* __restrict__ g1,
    const float* __restrict__ be1, float* __restrict__ h1)
{
    __shared__ float eT[DD][20];      // transposed emb tile, padded (80B rows, 16B aligned)
    __shared__ float red[4][16][2];
    __shared__ float stats[16][2];
    const int t  = threadIdx.x;
    const int rb = blockIdx.x * 16;

    const float* src = emb + (size_t)rb * DD;
    #pragma unroll
    for (int k = 0; k < 48; ++k) {
        int idx = t + k * 256;        // 16*768 = 12288 floats
        eT[idx % DD][idx / DD] = src[idx];
    }
    __syncthreads();

    const int c0 = t, c1 = t + 256;
    float acc0[16], acc1[16];
    #pragma unroll
    for (int r = 0; r < 16; ++r) { acc0[r] = 0.f; acc1[r] = 0.f; }

    for (int d = 0; d < DD; ++d) {
        float w0 = W1[d * NH1 + c0];
        float w1 = W1[d * NH1 + c1];
        float ev[16];
        *(float4*)&ev[0]  = *(const float4*)&eT[d][0];
        *(float4*)&ev[4]  = *(const float4*)&eT[d][4];
        *(float4*)&ev[8]  = *(const float4*)&eT[d][8];
        *(float4*)&ev[12] = *(const float4*)&eT[d][12];
        #pragma unroll
        for (int r = 0; r < 16; ++r) {
            acc0[r] = fmaf(ev[r], w0, acc0[r]);
            acc1[r] = fmaf(ev[r], w1, acc1[r]);
        }
    }
    const float bb0 = b1[c0], bb1 = b1[c1];
    #pragma unroll
    for (int r = 0; r < 16; ++r) { acc0[r] += bb0; acc1[r] += bb1; }

    const int wid = t >> 6, lane = t & 63;
    #pragma unroll
    for (int r = 0; r < 16; ++r) {
        float p = acc0[r] + acc1[r];
        float q = acc0[r] * acc0[r] + acc1[r] * acc1[r];
        #pragma unroll
        for (int off = 32; off; off >>= 1) {
            p += __shfl_xor(p, off);
            q += __shfl_xor(q, off);
        }
        if (lane == 0) { red[wid][r][0] = p; red[wid][r][1] = q; }
    }
    __syncthreads();
    if (t < 16) {
        float S  = red[0][t][0] + red[1][t][0] + red[2][t][0] + red[3][t][0];
        float S2 = red[0][t][1] + red[1][t][1] + red[2][t][1] + red[3][t][1];
        float mu  = S  * (1.f / NH1);
        float var = S2 * (1.f / NH1) - mu * mu;
        stats[t][0] = mu;
        stats[t][1] = rsqrtf(var + 1e-5f);
    }
    __syncthreads();
    const float gg0 = g1[c0], gg1 = g1[c1], eb0 = be1[c0], eb1 = be1[c1];
    float* dst = h1 + (size_t)rb * NH1;
    #pragma unroll
    for (int r = 0; r < 16; ++r) {
        float mu = stats[r][0], rs = stats[r][1];
        dst[r * NH1 + c0] = fmaxf(fmaf((acc0[r] - mu) * rs, gg0, eb0), 0.f);
        dst[r * NH1 + c1] = fmaxf(fmaf((acc1[r] - mu) * rs, gg1, eb1), 0.f);
    }
}

// ---------------------------------------------------------------------------
// k2: h2 = relu(LN(h1 @ W2 + b2))   h1 (B,512)  W2 (512,256)  h2 (B,256)
// block: 256 threads, 16 rows. Each thread: col t, 16 rows.
__global__ __launch_bounds__(256) void k_gemm_ln2(
    const float* __restrict__ h1, const float* __restrict__ W2,
    const float* __restrict__ b2, const float* __restrict__ g2,
    const float* __restrict__ be2, float* __restrict__ h2)
{
    __shared__ float hT[NH1][20];
    __shared__ float red[4][16][2];
    __shared__ float stats[16][2];
    const int t  = threadIdx.x;
    const int rb = blockIdx.x * 16;

    const float* src = h1 + (size_t)rb * NH1;
    #pragma unroll
    for (int k = 0; k < 32; ++k) {
        int idx = t + k * 256;        // 16*512 = 8192 floats
        hT[idx % NH1][idx / NH1] = src[idx];
    }
    __syncthreads();

    float acc[16];
    #pragma unroll
    for (int r = 0; r < 16; ++r) acc[r] = 0.f;

    for (int d = 0; d < NH1; ++d) {
        float w = W2[d * NH2 + t];
        float ev[16];
        *(float4*)&ev[0]  = *(const float4*)&hT[d][0];
        *(float4*)&ev[4]  = *(const float4*)&hT[d][4];
        *(float4*)&ev[8]  = *(const float4*)&hT[d][8];
        *(float4*)&ev[12] = *(const float4*)&hT[d][12];
        #pragma unroll
        for (int r = 0; r < 16; ++r) acc[r] = fmaf(ev[r], w, acc[r]);
    }
    const float bb = b2[t];
    #pragma unroll
    for (int r = 0; r < 16; ++r) acc[r] += bb;

    const int wid = t >> 6, lane = t & 63;
    #pragma unroll
    for (int r = 0; r < 16; ++r) {
        float p = acc[r];
        float q = acc[r] * acc[r];
        #pragma unroll
        for (int off = 32; off; off >>= 1) {
            p += __shfl_xor(p, off);
            q += __shfl_xor(q, off);
        }
        if (lane == 0) { red[wid][r][0] = p; red[wid][r][1] = q; }
    }
    __syncthreads();
    if (t < 16) {
        float S  = red[0][t][0] + red[1][t][0] + red[2][t][0] + red[3][t][0];
        float S2 = red[0][t][1] + red[1][t][1] + red[2][t][1] + red[3][t][1];
        float mu  = S  * (1.f / NH2);
        float var = S2 * (1.f / NH2) - mu * mu;
        stats[t][0] = mu;
        stats[t][1] = rsqrtf(var + 1e-5f);
    }
    __syncthreads();
    const float gg = g2[t], eb = be2[t];
    float* dst = h2 + (size_t)rb * NH2;
    #pragma unroll
    for (int r = 0; r < 16; ++r) {
        float mu = stats[r][0], rs = stats[r][1];
        dst[r * NH2 + t] = fmaxf(fmaf((acc[r] - mu) * rs, gg, eb), 0.f);
    }
}

// ---------------------------------------------------------------------------
// k3a: W_flat = h2 @ Wd + bd   h2 (B,256)  Wd (256,3072) -> d_out W region
// block: 256 threads; 32 rows x 256 cols. thread: cols {cb+cc, cb+cc+128},
// rows half*16..half*16+15.
__global__ __launch_bounds__(256) void k_gemm_wd(
    const float* __restrict__ h2, const float* __restrict__ Wd,
    const float* __restrict__ bd, float* __restrict__ wflat)
{
    __shared__ float hT[NH2][36];     // 144B rows, 16B aligned
    const int t  = threadIdx.x;
    const int rb = blockIdx.x * 32;
    const int cb = blockIdx.y * 256;

    const float* src = h2 + (size_t)rb * NH2;
    #pragma unroll
    for (int k = 0; k < 32; ++k) {
        int idx = t + k * 256;        // 32*256 = 8192 floats
        hT[idx % NH2][idx / NH2] = src[idx];
    }
    __syncthreads();

    const int cc   = t & 127;
    const int half = t >> 7;
    const int c0 = cb + cc, c1 = cb + cc + 128;
    const int r0 = half * 16;

    float acc0[16], acc1[16];
    #pragma unroll
    for (int r = 0; r < 16; ++r) { acc0[r] = 0.f; acc1[r] = 0.f; }

    for (int d = 0; d < NH2; ++d) {
        float w0 = Wd[(size_t)d * (KK * DD) + c0];
        float w1 = Wd[(size_t)d * (KK * DD) + c1];
        float ev[16];
        *(float4*)&ev[0]  = *(const float4*)&hT[d][r0 + 0];
        *(float4*)&ev[4]  = *(const float4*)&hT[d][r0 + 4];
        *(float4*)&ev[8]  = *(const float4*)&hT[d][r0 + 8];
        *(float4*)&ev[12] = *(const float4*)&hT[d][r0 + 12];
        #pragma unroll
        for (int r = 0; r < 16; ++r) {
            acc0[r] = fmaf(ev[r], w0, acc0[r]);
            acc1[r] = fmaf(ev[r], w1, acc1[r]);
        }
    }
    const float bias0 = bd[c0], bias1 = bd[c1];
    float* dst = wflat + (size_t)rb * (KK * DD);
    #pragma unroll
    for (int r = 0; r < 16; ++r) {
        dst[(size_t)(r0 + r) * (KK * DD) + c0] = acc0[r] + bias0;
        dst[(size_t)(r0 + r) * (KK * DD) + c1] = acc1[r] + bias1;
    }
}

// ---------------------------------------------------------------------------
// k3b: attn = softmax(h2 @ Wa + ba)   h2 (B,256)  Wa (256,768) -> attn region
// block: 256 threads, 16 rows. thread: cols {t, t+256, t+512}.
__global__ __launch_bounds__(256) void k_attn(
    const float* __restrict__ h2, const float* __restrict__ Wa,
    const float* __restrict__ ba, float* __restrict__ attn)
{
    __shared__ float hT[NH2][20];
    __shared__ float red[4][16];
    __shared__ float stats[16];
    const int t  = threadIdx.x;
    const int rb = blockIdx.x * 16;

    const float* src = h2 + (size_t)rb * NH2;
    #pragma unroll
    for (int k = 0; k < 16; ++k) {
        int idx = t + k * 256;        // 16*256 = 4096 floats
        hT[idx % NH2][idx / NH2] = src[idx];
    }
    __syncthreads();

    float a0[16], a1[16], a2[16];
    #pragma unroll
    for (int r = 0; r < 16; ++r) { a0[r] = 0.f; a1[r] = 0.f; a2[r] = 0.f; }

    for (int d = 0; d < NH2; ++d) {
        float w0 = Wa[d * DD + t];
        float w1 = Wa[d * DD + t + 256];
        float w2 = Wa[d * DD + t + 512];
        float ev[16];
        *(float4*)&ev[0]  = *(const float4*)&hT[d][0];
        *(float4*)&ev[4]  = *(const float4*)&hT[d][4];
        *(float4*)&ev[8]  = *(const float4*)&hT[d][8];
        *(float4*)&ev[12] = *(const float4*)&hT[d][12];
        #pragma unroll
        for (int r = 0; r < 16; ++r) {
            a0[r] = fmaf(ev[r], w0, a0[r]);
            a1[r] = fmaf(ev[r], w1, a1[r]);
            a2[r] = fmaf(ev[r], w2, a2[r]);
        }
    }
    const float bb0 = ba[t], bb1 = ba[t + 256], bb2 = ba[t + 512];
    #pragma unroll
    for (int r = 0; r < 16; ++r) { a0[r] += bb0; a1[r] += bb1; a2[r] += bb2; }

    const int wid = t >> 6, lane = t & 63;
    // row max
    #pragma unroll
    for (int r = 0; r < 16; ++r) {
        float m = fmaxf(a0[r], fmaxf(a1[r], a2[r]));
        #pragma unroll
        for (int off = 32; off; off >>= 1) m = fmaxf(m, __shfl_xor(m, off));
        if (lane == 0) red[wid][r] = m;
    }
    __syncthreads();
    if (t < 16)
        stats[t] = fmaxf(fmaxf(red[0][t], red[1][t]), fmaxf(red[2][t], red[3][t]));
    __syncthreads();
    // exp
    #pragma unroll
    for (int r = 0; r < 16; ++r) {
        float M = stats[r];
        a0[r] = __expf(a0[r] - M);
        a1[r] = __expf(a1[r] - M);
        a2[r] = __expf(a2[r] - M);
    }
    // row sum
    #pragma unroll
    for (int r = 0; r < 16; ++r) {
        float s = a0[r] + a1[r] + a2[r];
        #pragma unroll
        for (int off = 32; off; off >>= 1) s += __shfl_xor(s, off);
        if (lane == 0) red[wid][r] = s;
    }
    __syncthreads();
    if (t < 16)
        stats[t] = 1.f / (red[0][t] + red[1][t] + red[2][t] + red[3][t]);
    __syncthreads();

    float* dst = attn + (size_t)rb * DD;
    #pragma unroll
    for (int r = 0; r < 16; ++r) {
        float inv = stats[r];
        dst[r * DD + t]       = a0[r] * inv;
        dst[r * DD + t + 256] = a1[r] * inv;
        dst[r * DD + t + 512] = a2[r] * inv;
    }
}

// ---------------------------------------------------------------------------
// k4: per row: W = W_flat.reshape(K,D) * attn; modified Gram-Schmidt; normalize.
// One wave per row, 4 rows per block. In-place on d_out W region.
__global__ __launch_bounds__(256) void k_gs(float* __restrict__ out)
{
    const int wid  = threadIdx.x >> 6;
    const int lane = threadIdx.x & 63;
    const size_t row = (size_t)blockIdx.x * 4 + wid;

    float* Wf = out + row * (KK * DD);
    const float* at = out + (size_t)BSZ * (KK * DD) + row * DD;

    float a[12];
    #pragma unroll
    for (int k = 0; k < 3; ++k) {
        float4 av = *(const float4*)&at[lane * 4 + 256 * k];
        a[k * 4 + 0] = av.x; a[k * 4 + 1] = av.y;
        a[k * 4 + 2] = av.z; a[k * 4 + 3] = av.w;
    }
    float w[4][12];
    #pragma unroll
    for (int i = 0; i < 4; ++i) {
        #pragma unroll
        for (int k = 0; k < 3; ++k) {
            float4 wv = *(const float4*)&Wf[i * DD + lane * 4 + 256 * k];
            w[i][k * 4 + 0] = wv.x * a[k * 4 + 0];
            w[i][k * 4 + 1] = wv.y * a[k * 4 + 1];
            w[i][k * 4 + 2] = wv.z * a[k * 4 + 2];
            w[i][k * 4 + 3] = wv.w * a[k * 4 + 3];
        }
    }
    // modified Gram-Schmidt (matches reference update order)
    #pragma unroll
    for (int i = 0; i < 4; ++i) {
        #pragma unroll
        for (int p = 0; p < i; ++p) {
            float s = 0.f;
            #pragma unroll
            for (int j = 0; j < 12; ++j) s = fmaf(w[i][j], w[p][j], s);
            #pragma unroll
            for (int off = 32; off; off >>= 1) s += __shfl_xor(s, off);
            #pragma unroll
            for (int j = 0; j < 12; ++j) w[i][j] = fmaf(-s, w[p][j], w[i][j]);
        }
        float n2 = 0.f;
        #pragma unroll
        for (int j = 0; j < 12; ++j) n2 = fmaf(w[i][j], w[i][j], n2);
        #pragma unroll
        for (int off = 32; off; off >>= 1) n2 += __shfl_xor(n2, off);
        float inv = 1.f / fmaxf(sqrtf(n2), 1e-12f);
        #pragma unroll
        for (int j = 0; j < 12; ++j) w[i][j] *= inv;
    }
    #pragma unroll
    for (int i = 0; i < 4; ++i) {
        #pragma unroll
        for (int k = 0; k < 3; ++k) {
            float4 wv;
            wv.x = w[i][k * 4 + 0]; wv.y = w[i][k * 4 + 1];
            wv.z = w[i][k * 4 + 2]; wv.w = w[i][k * 4 + 3];
            *(float4*)&Wf[i * DD + lane * 4 + 256 * k] = wv;
        }
    }
}

// ---------------------------------------------------------------------------
extern "C" void kernel_launch(void* const* d_in, const int* in_sizes, int n_in,
                              void* d_out, int out_size, void* d_ws, size_t ws_size,
                              hipStream_t stream)
{
    const float* emb = (const float*)d_in[0];
    const float* W1  = (const float*)d_in[1];
    const float* b1  = (const float*)d_in[2];
    const float* g1  = (const float*)d_in[3];
    const float* be1 = (const float*)d_in[4];
    const float* W2  = (const float*)d_in[5];
    const float* b2  = (const float*)d_in[6];
    const float* g2  = (const float*)d_in[7];
    const float* be2 = (const float*)d_in[8];
    const float* Wd  = (const float*)d_in[9];
    const float* bd  = (const float*)d_in[10];
    const float* Wa  = (const float*)d_in[11];
    const float* ba  = (const float*)d_in[12];

    float* out  = (float*)d_out;
    float* h1   = (float*)d_ws;                       // B*512 f32 = 33.5 MB
    float* h2   = h1 + (size_t)BSZ * NH1;             // B*256 f32 = 16.8 MB
    float* wfl  = out;                                // W region, B*K*D
    float* attn = out + (size_t)BSZ * KK * DD;        // attn region, B*D

    hipLaunchKernelGGL(k_gemm_ln1, dim3(BSZ / 16), dim3(256), 0, stream,
                       emb, W1, b1, g1, be1, h1);
    hipLaunchKernelGGL(k_gemm_ln2, dim3(BSZ / 16), dim3(256), 0, stream,
                       h1, W2, b2, g2, be2, h2);
    hipLaunchKernelGGL(k_gemm_wd, dim3(BSZ / 32, (KK * DD) / 256), dim3(256), 0, stream,
                       h2, Wd, bd, wfl);
    hipLaunchKernelGGL(k_attn, dim3(BSZ / 16), dim3(256), 0, stream,
                       h2, Wa, ba, attn);
    hipLaunchKernelGGL(k_gs, dim3(BSZ / 4), dim3(256), 0, stream, out);
}

// Round 3
// 644.545 us; speedup vs baseline: 1.2552x; 1.2552x over previous
//
#include <hip/hip_runtime.h>
#include <hip/hip_bf16.h>

#define BSZ 16384
#define DD  768
#define KK  4
#define NH1 512
#define NH2 256
#define ND  (KK * DD)   // 3072

typedef __bf16 bf16x8 __attribute__((ext_vector_type(8)));
typedef float  f32x4  __attribute__((ext_vector_type(4)));

// ---------------------------------------------------------------------------
// k1: h1 = relu(LN(emb @ W1 + b1))   (unchanged fp32, target for next round)
__global__ __launch_bounds__(256) void k_gemm_ln1(
    const float* __restrict__ emb, const float* __restrict__ W1,
    const float* __restrict__ b1, const float* __restrict__ g1,
    const float* __restrict__ be1, float* __restrict__ h1)
{
    __shared__ float eT[DD][20];
    __shared__ float red[4][16][2];
    __shared__ float stats[16][2];
    const int t  = threadIdx.x;
    const int rb = blockIdx.x * 16;

    const float* src = emb + (size_t)rb * DD;
    #pragma unroll
    for (int k = 0; k < 48; ++k) {
        int idx = t + k * 256;
        eT[idx % DD][idx / DD] = src[idx];
    }
    __syncthreads();

    const int c0 = t, c1 = t + 256;
    float acc0[16], acc1[16];
    #pragma unroll
    for (int r = 0; r < 16; ++r) { acc0[r] = 0.f; acc1[r] = 0.f; }

    for (int d = 0; d < DD; ++d) {
        float w0 = W1[d * NH1 + c0];
        float w1 = W1[d * NH1 + c1];
        float ev[16];
        *(float4*)&ev[0]  = *(const float4*)&eT[d][0];
        *(float4*)&ev[4]  = *(const float4*)&eT[d][4];
        *(float4*)&ev[8]  = *(const float4*)&eT[d][8];
        *(float4*)&ev[12] = *(const float4*)&eT[d][12];
        #pragma unroll
        for (int r = 0; r < 16; ++r) {
            acc0[r] = fmaf(ev[r], w0, acc0[r]);
            acc1[r] = fmaf(ev[r], w1, acc1[r]);
        }
    }
    const float bb0 = b1[c0], bb1 = b1[c1];
    #pragma unroll
    for (int r = 0; r < 16; ++r) { acc0[r] += bb0; acc1[r] += bb1; }

    const int wid = t >> 6, lane = t & 63;
    #pragma unroll
    for (int r = 0; r < 16; ++r) {
        float p = acc0[r] + acc1[r];
        float q = acc0[r] * acc0[r] + acc1[r] * acc1[r];
        #pragma unroll
        for (int off = 32; off; off >>= 1) {
            p += __shfl_xor(p, off);
            q += __shfl_xor(q, off);
        }
        if (lane == 0) { red[wid][r][0] = p; red[wid][r][1] = q; }
    }
    __syncthreads();
    if (t < 16) {
        float S  = red[0][t][0] + red[1][t][0] + red[2][t][0] + red[3][t][0];
        float S2 = red[0][t][1] + red[1][t][1] + red[2][t][1] + red[3][t][1];
        float mu  = S  * (1.f / NH1);
        float var = S2 * (1.f / NH1) - mu * mu;
        stats[t][0] = mu;
        stats[t][1] = rsqrtf(var + 1e-5f);
    }
    __syncthreads();
    const float gg0 = g1[c0], gg1 = g1[c1], eb0 = be1[c0], eb1 = be1[c1];
    float* dst = h1 + (size_t)rb * NH1;
    #pragma unroll
    for (int r = 0; r < 16; ++r) {
        float mu = stats[r][0], rs = stats[r][1];
        dst[r * NH1 + c0] = fmaxf(fmaf((acc0[r] - mu) * rs, gg0, eb0), 0.f);
        dst[r * NH1 + c1] = fmaxf(fmaf((acc1[r] - mu) * rs, gg1, eb1), 0.f);
    }
}

// ---------------------------------------------------------------------------
// k2: h2 = relu(LN(h1 @ W2 + b2)) -> h2 stored as bf16
__global__ __launch_bounds__(256) void k_gemm_ln2(
    const float* __restrict__ h1, const float* __restrict__ W2,
    const float* __restrict__ b2, const float* __restrict__ g2,
    const float* __restrict__ be2, __hip_bfloat16* __restrict__ h2)
{
    __shared__ float hT[NH1][20];
    __shared__ float red[4][16][2];
    __shared__ float stats[16][2];
    const int t  = threadIdx.x;
    const int rb = blockIdx.x * 16;

    const float* src = h1 + (size_t)rb * NH1;
    #pragma unroll
    for (int k = 0; k < 32; ++k) {
        int idx = t + k * 256;
        hT[idx % NH1][idx / NH1] = src[idx];
    }
    __syncthreads();

    float acc[16];
    #pragma unroll
    for (int r = 0; r < 16; ++r) acc[r] = 0.f;

    for (int d = 0; d < NH1; ++d) {
        float w = W2[d * NH2 + t];
        float ev[16];
        *(float4*)&ev[0]  = *(const float4*)&hT[d][0];
        *(float4*)&ev[4]  = *(const float4*)&hT[d][4];
        *(float4*)&ev[8]  = *(const float4*)&hT[d][8];
        *(float4*)&ev[12] = *(const float4*)&hT[d][12];
        #pragma unroll
        for (int r = 0; r < 16; ++r) acc[r] = fmaf(ev[r], w, acc[r]);
    }
    const float bb = b2[t];
    #pragma unroll
    for (int r = 0; r < 16; ++r) acc[r] += bb;

    const int wid = t >> 6, lane = t & 63;
    #pragma unroll
    for (int r = 0; r < 16; ++r) {
        float p = acc[r];
        float q = acc[r] * acc[r];
        #pragma unroll
        for (int off = 32; off; off >>= 1) {
            p += __shfl_xor(p, off);
            q += __shfl_xor(q, off);
        }
        if (lane == 0) { red[wid][r][0] = p; red[wid][r][1] = q; }
    }
    __syncthreads();
    if (t < 16) {
        float S  = red[0][t][0] + red[1][t][0] + red[2][t][0] + red[3][t][0];
        float S2 = red[0][t][1] + red[1][t][1] + red[2][t][1] + red[3][t][1];
        float mu  = S  * (1.f / NH2);
        float var = S2 * (1.f / NH2) - mu * mu;
        stats[t][0] = mu;
        stats[t][1] = rsqrtf(var + 1e-5f);
    }
    __syncthreads();
    const float gg = g2[t], eb = be2[t];
    __hip_bfloat16* dst = h2 + (size_t)rb * NH2;
    #pragma unroll
    for (int r = 0; r < 16; ++r) {
        float mu = stats[r][0], rs = stats[r][1];
        dst[r * NH2 + t] =
            __float2bfloat16(fmaxf(fmaf((acc[r] - mu) * rs, gg, eb), 0.f));
    }
}

// ---------------------------------------------------------------------------
// k_wd_cvt: Wd (256 x 3072 f32) -> Wd_t (3072 x 256 bf16), LDS-tiled transpose
__global__ __launch_bounds__(256) void k_wd_cvt(
    const float* __restrict__ Wd, __hip_bfloat16* __restrict__ Wdt)
{
    __shared__ float tile[32][33];
    const int kb = blockIdx.y * 32;   // along K=256
    const int cb = blockIdx.x * 32;   // along N=3072
    const int t = threadIdx.x;
    const int r = t >> 5, c = t & 31;
    #pragma unroll
    for (int i = 0; i < 4; ++i)
        tile[r + i * 8][c] = Wd[(size_t)(kb + r + i * 8) * ND + cb + c];
    __syncthreads();
    #pragma unroll
    for (int i = 0; i < 4; ++i)
        Wdt[(size_t)(cb + r + i * 8) * NH2 + kb + c] =
            __float2bfloat16(tile[c][r + i * 8]);
}

// ---------------------------------------------------------------------------
// k3a (MFMA): W_flat = h2 @ Wd + bd
// h2 (B,256) bf16 row-major; Wd_t (3072,256) bf16 row-major (= Wd^T).
// Block: 256 thr = 4 waves (2x2), tile 128x128, wave tile 64x64 (4x4 frags).
// BK=64, single-buffered padded LDS [128][72] bf16 (2-way bank alias = free).
// FIX (round 2 NaN): K-slice = 128 rows x 64 bf16 = 1024 x 16B chunks per
// matrix -> 4 chunks/thread (was 2: only k<32 staged, kk=1 read garbage LDS).
__global__ __launch_bounds__(256) void k_gemm_wd_mfma(
    const ushort* __restrict__ h2, const ushort* __restrict__ Wdt,
    const float* __restrict__ bd, float* __restrict__ wflat)
{
    __shared__ ushort Asm[128 * 72];
    __shared__ ushort Bsm[128 * 72];

    const int t    = threadIdx.x;
    const int lane = t & 63;
    const int wid  = t >> 6;
    const int wm   = wid >> 1;          // 0..1
    const int wn   = wid & 1;           // 0..1
    const int l16  = lane & 15;
    const int g8   = (lane >> 4) * 8;   // K sub-offset for A/B frags
    const int g4   = (lane >> 4) * 4;   // row sub-offset for C/D

    const int rb = blockIdx.y * 128;    // M tile
    const int cb = blockIdx.x * 128;    // N tile

    f32x4 acc[4][4] = {};

    for (int ks = 0; ks < 4; ++ks) {
        const int k0 = ks * 64;
        // global -> regs (issued before barrier; latency overlaps prior MFMA)
        int4 ra[4], rbv[4];
        #pragma unroll
        for (int i = 0; i < 4; ++i) {
            int ch  = t + i * 256;           // 1024 chunks of 16B per matrix
            int row = ch >> 3;               // 128 rows, 8 chunks/row (64 bf16)
            int sl  = ch & 7;
            ra[i]  = *(const int4*)&h2 [(size_t)(rb + row) * NH2 + k0 + sl * 8];
            rbv[i] = *(const int4*)&Wdt[(size_t)(cb + row) * NH2 + k0 + sl * 8];
        }
        __syncthreads();   // all waves done reading previous tile
        #pragma unroll
        for (int i = 0; i < 4; ++i) {
            int ch  = t + i * 256;
            int row = ch >> 3;
            int sl  = ch & 7;
            *(int4*)&Asm[row * 72 + sl * 8] = ra[i];
            *(int4*)&Bsm[row * 72 + sl * 8] = rbv[i];
        }
        __syncthreads();   // staging visible

        #pragma unroll
        for (int kk = 0; kk < 2; ++kk) {
            bf16x8 af[4], bfr[4];
            #pragma unroll
            for (int m = 0; m < 4; ++m)
                af[m] = *(const bf16x8*)&Asm[(wm * 64 + m * 16 + l16) * 72 + kk * 32 + g8];
            #pragma unroll
            for (int n = 0; n < 4; ++n)
                bfr[n] = *(const bf16x8*)&Bsm[(wn * 64 + n * 16 + l16) * 72 + kk * 32 + g8];
            #pragma unroll
            for (int m = 0; m < 4; ++m)
                #pragma unroll
                for (int n = 0; n < 4; ++n)
                    acc[m][n] = __builtin_amdgcn_mfma_f32_16x16x32_bf16(
                        af[m], bfr[n], acc[m][n], 0, 0, 0);
        }
    }

    // epilogue: C = acc + bias
    float bv[4];
    #pragma unroll
    for (int n = 0; n < 4; ++n)
        bv[n] = bd[cb + wn * 64 + n * 16 + l16];

    #pragma unroll
    for (int m = 0; m < 4; ++m) {
        const int row0 = rb + wm * 64 + m * 16 + g4;
        #pragma unroll
        for (int n = 0; n < 4; ++n) {
            const int col = cb + wn * 64 + n * 16 + l16;
            #pragma unroll
            for (int j = 0; j < 4; ++j)
                wflat[(size_t)(row0 + j) * ND + col] = acc[m][n][j] + bv[n];
        }
    }
}

// ---------------------------------------------------------------------------
// k3b: attn = softmax(h2 @ Wa + ba)  (h2 bf16)
__global__ __launch_bounds__(256) void k_attn(
    const __hip_bfloat16* __restrict__ h2, const float* __restrict__ Wa,
    const float* __restrict__ ba, float* __restrict__ attn)
{
    __shared__ float hT[NH2][20];
    __shared__ float red[4][16];
    __shared__ float stats[16];
    const int t  = threadIdx.x;
    const int rb = blockIdx.x * 16;

    const __hip_bfloat16* src = h2 + (size_t)rb * NH2;
    #pragma unroll
    for (int k = 0; k < 16; ++k) {
        int idx = t + k * 256;
        hT[idx % NH2][idx / NH2] = __bfloat162float(src[idx]);
    }
    __syncthreads();

    float a0[16], a1[16], a2[16];
    #pragma unroll
    for (int r = 0; r < 16; ++r) { a0[r] = 0.f; a1[r] = 0.f; a2[r] = 0.f; }

    for (int d = 0; d < NH2; ++d) {
        float w0 = Wa[d * DD + t];
        float w1 = Wa[d * DD + t + 256];
        float w2 = Wa[d * DD + t + 512];
        float ev[16];
        *(float4*)&ev[0]  = *(const float4*)&hT[d][0];
        *(float4*)&ev[4]  = *(const float4*)&hT[d][4];
        *(float4*)&ev[8]  = *(const float4*)&hT[d][8];
        *(float4*)&ev[12] = *(const float4*)&hT[d][12];
        #pragma unroll
        for (int r = 0; r < 16; ++r) {
            a0[r] = fmaf(ev[r], w0, a0[r]);
            a1[r] = fmaf(ev[r], w1, a1[r]);
            a2[r] = fmaf(ev[r], w2, a2[r]);
        }
    }
    const float bb0 = ba[t], bb1 = ba[t + 256], bb2 = ba[t + 512];
    #pragma unroll
    for (int r = 0; r < 16; ++r) { a0[r] += bb0; a1[r] += bb1; a2[r] += bb2; }

    const int wid = t >> 6, lane = t & 63;
    #pragma unroll
    for (int r = 0; r < 16; ++r) {
        float m = fmaxf(a0[r], fmaxf(a1[r], a2[r]));
        #pragma unroll
        for (int off = 32; off; off >>= 1) m = fmaxf(m, __shfl_xor(m, off));
        if (lane == 0) red[wid][r] = m;
    }
    __syncthreads();
    if (t < 16)
        stats[t] = fmaxf(fmaxf(red[0][t], red[1][t]), fmaxf(red[2][t], red[3][t]));
    __syncthreads();
    #pragma unroll
    for (int r = 0; r < 16; ++r) {
        float M = stats[r];
        a0[r] = __expf(a0[r] - M);
        a1[r] = __expf(a1[r] - M);
        a2[r] = __expf(a2[r] - M);
    }
    #pragma unroll
    for (int r = 0; r < 16; ++r) {
        float s = a0[r] + a1[r] + a2[r];
        #pragma unroll
        for (int off = 32; off; off >>= 1) s += __shfl_xor(s, off);
        if (lane == 0) red[wid][r] = s;
    }
    __syncthreads();
    if (t < 16)
        stats[t] = 1.f / (red[0][t] + red[1][t] + red[2][t] + red[3][t]);
    __syncthreads();

    float* dst = attn + (size_t)rb * DD;
    #pragma unroll
    for (int r = 0; r < 16; ++r) {
        float inv = stats[r];
        dst[r * DD + t]       = a0[r] * inv;
        dst[r * DD + t + 256] = a1[r] * inv;
        dst[r * DD + t + 512] = a2[r] * inv;
    }
}

// ---------------------------------------------------------------------------
// k4: per row: W = W_flat.reshape(K,D) * attn; modified Gram-Schmidt; normalize.
__global__ __launch_bounds__(256) void k_gs(float* __restrict__ out)
{
    const int wid  = threadIdx.x >> 6;
    const int lane = threadIdx.x & 63;
    const size_t row = (size_t)blockIdx.x * 4 + wid;

    float* Wf = out + row * (KK * DD);
    const float* at = out + (size_t)BSZ * (KK * DD) + row * DD;

    float a[12];
    #pragma unroll
    for (int k = 0; k < 3; ++k) {
        float4 av = *(const float4*)&at[lane * 4 + 256 * k];
        a[k * 4 + 0] = av.x; a[k * 4 + 1] = av.y;
        a[k * 4 + 2] = av.z; a[k * 4 + 3] = av.w;
    }
    float w[4][12];
    #pragma unroll
    for (int i = 0; i < 4; ++i) {
        #pragma unroll
        for (int k = 0; k < 3; ++k) {
            float4 wv = *(const float4*)&Wf[i * DD + lane * 4 + 256 * k];
            w[i][k * 4 + 0] = wv.x * a[k * 4 + 0];
            w[i][k * 4 + 1] = wv.y * a[k * 4 + 1];
            w[i][k * 4 + 2] = wv.z * a[k * 4 + 2];
            w[i][k * 4 + 3] = wv.w * a[k * 4 + 3];
        }
    }
    #pragma unroll
    for (int i = 0; i < 4; ++i) {
        #pragma unroll
        for (int p = 0; p < i; ++p) {
            float s = 0.f;
            #pragma unroll
            for (int j = 0; j < 12; ++j) s = fmaf(w[i][j], w[p][j], s);
            #pragma unroll
            for (int off = 32; off; off >>= 1) s += __shfl_xor(s, off);
            #pragma unroll
            for (int j = 0; j < 12; ++j) w[i][j] = fmaf(-s, w[p][j], w[i][j]);
        }
        float n2 = 0.f;
        #pragma unroll
        for (int j = 0; j < 12; ++j) n2 = fmaf(w[i][j], w[i][j], n2);
        #pragma unroll
        for (int off = 32; off; off >>= 1) n2 += __shfl_xor(n2, off);
        float inv = 1.f / fmaxf(sqrtf(n2), 1e-12f);
        #pragma unroll
        for (int j = 0; j < 12; ++j) w[i][j] *= inv;
    }
    #pragma unroll
    for (int i = 0; i < 4; ++i) {
        #pragma unroll
        for (int k = 0; k < 3; ++k) {
            float4 wv;
            wv.x = w[i][k * 4 + 0]; wv.y = w[i][k * 4 + 1];
            wv.z = w[i][k * 4 + 2]; wv.w = w[i][k * 4 + 3];
            *(float4*)&Wf[i * DD + lane * 4 + 256 * k] = wv;
        }
    }
}

// ---------------------------------------------------------------------------
extern "C" void kernel_launch(void* const* d_in, const int* in_sizes, int n_in,
                              void* d_out, int out_size, void* d_ws, size_t ws_size,
                              hipStream_t stream)
{
    const float* emb = (const float*)d_in[0];
    const float* W1  = (const float*)d_in[1];
    const float* b1  = (const float*)d_in[2];
    const float* g1  = (const float*)d_in[3];
    const float* be1 = (const float*)d_in[4];
    const float* W2  = (const float*)d_in[5];
    const float* b2  = (const float*)d_in[6];
    const float* g2  = (const float*)d_in[7];
    const float* be2 = (const float*)d_in[8];
    const float* Wd  = (const float*)d_in[9];
    const float* bd  = (const float*)d_in[10];
    const float* Wa  = (const float*)d_in[11];
    const float* ba  = (const float*)d_in[12];

    float* out = (float*)d_out;
    float* h1  = (float*)d_ws;                                   // B*512 f32 = 33.5 MB
    __hip_bfloat16* h2  = (__hip_bfloat16*)(h1 + (size_t)BSZ * NH1);  // B*256 bf16 = 8.4 MB
    __hip_bfloat16* Wdt = h2 + (size_t)BSZ * NH2;                // 3072*256 bf16 = 1.5 MB
    float* wfl  = out;                                           // W region, B*K*D
    float* attn = out + (size_t)BSZ * KK * DD;                   // attn region, B*D

    hipLaunchKernelGGL(k_wd_cvt, dim3(ND / 32, NH2 / 32), dim3(256), 0, stream,
                       Wd, Wdt);
    hipLaunchKernelGGL(k_gemm_ln1, dim3(BSZ / 16), dim3(256), 0, stream,
                       emb, W1, b1, g1, be1, h1);
    hipLaunchKernelGGL(k_gemm_ln2, dim3(BSZ / 16), dim3(256), 0, stream,
                       h1, W2, b2, g2, be2, h2);
    hipLaunchKernelGGL(k_gemm_wd_mfma, dim3(ND / 128, BSZ / 128), dim3(256), 0, stream,
                       (const ushort*)h2, (const ushort*)Wdt, bd, wfl);
    hipLaunchKernelGGL(k_attn, dim3(BSZ / 16), dim3(256), 0, stream,
                       h2, Wa, ba, attn);
    hipLaunchKernelGGL(k_gs, dim3(BSZ / 4), dim3(256), 0, stream, out);
}

// Round 4
// 508.099 us; speedup vs baseline: 1.5923x; 1.2685x over previous
//
#include <hip/hip_runtime.h>
#include <hip/hip_bf16.h>

#define BSZ 16384
#define DD  768
#define KK  4
#define NH1 512
#define NH2 256
#define ND  (KK * DD)   // 3072

typedef __bf16 bf16x8 __attribute__((ext_vector_type(8)));
typedef float  f32x4  __attribute__((ext_vector_type(4)));

static __device__ __forceinline__ float bf2f(ushort u) {
    union { unsigned int i; float f; } v; v.i = (unsigned int)u << 16; return v.f;
}
static __device__ __forceinline__ ushort f2bf(float f) {
    return __bfloat16_as_ushort(__float2bfloat16(f));
}

// ---------------------------------------------------------------------------
// k_t_cvt: src (R x C f32) -> dst (C x R bf16)  [generic transpose+convert]
__global__ __launch_bounds__(256) void k_t_cvt(
    const float* __restrict__ src, ushort* __restrict__ dst, int R, int C)
{
    __shared__ float tile[32][33];
    const int rb0 = blockIdx.y * 32;  // src row
    const int cb0 = blockIdx.x * 32;  // src col
    const int t = threadIdx.x;
    const int r = t >> 5, c = t & 31;
    #pragma unroll
    for (int i = 0; i < 4; ++i)
        tile[r + i * 8][c] = src[(size_t)(rb0 + r + i * 8) * C + cb0 + c];
    __syncthreads();
    #pragma unroll
    for (int i = 0; i < 4; ++i)
        dst[(size_t)(cb0 + r + i * 8) * R + rb0 + c] = f2bf(tile[c][r + i * 8]);
}

// ---------------------------------------------------------------------------
// k1 (MFMA, fused LN+relu): h1 = relu(LN(emb @ W1 + b1)) stored bf16
// Tile 64 x 512 (full N so LN fuses in-block), BK=64, 12 K-steps.
// 512 thr = 8 waves, wave wn owns cols [wn*64, wn*64+64), frags 4x4.
// emb staged fp32->bf16 in regs; W1t pre-transposed bf16 (512 x 768).
__global__ __launch_bounds__(512) void k1_mfma(
    const float* __restrict__ emb, const ushort* __restrict__ W1t,
    const float* __restrict__ b1, const float* __restrict__ g1,
    const float* __restrict__ be1, ushort* __restrict__ h1)
{
    __shared__ ushort Asm[64 * 72];    //  9.2 KB
    __shared__ ushort Bsm[512 * 72];   // 73.7 KB
    __shared__ float red[8][64][2];    //  4 KB
    __shared__ float stats[64][2];

    const int t    = threadIdx.x;
    const int lane = t & 63;
    const int wn   = t >> 6;            // 0..7
    const int l16  = lane & 15;
    const int g8   = (lane >> 4) * 8;
    const int g4   = (lane >> 4) * 4;
    const int rb   = blockIdx.x * 64;

    const int arow = t >> 3, asl = t & 7;   // A: 512 chunks, 1/thread

    f32x4 acc[4][4] = {};

    for (int ks = 0; ks < 12; ++ks) {
        const int k0 = ks * 64;
        float4 a0 = *(const float4*)&emb[(size_t)(rb + arow) * DD + k0 + asl * 8];
        float4 a1 = *(const float4*)&emb[(size_t)(rb + arow) * DD + k0 + asl * 8 + 4];
        int4 rbv[8];
        #pragma unroll
        for (int i = 0; i < 8; ++i) {
            int ch = t + i * 512;           // B: 4096 chunks, 8/thread
            int row = ch >> 3, sl = ch & 7;
            rbv[i] = *(const int4*)&W1t[(size_t)row * DD + k0 + sl * 8];
        }
        __syncthreads();   // prev-tile reads done
        ushort av[8];
        av[0] = f2bf(a0.x); av[1] = f2bf(a0.y); av[2] = f2bf(a0.z); av[3] = f2bf(a0.w);
        av[4] = f2bf(a1.x); av[5] = f2bf(a1.y); av[6] = f2bf(a1.z); av[7] = f2bf(a1.w);
        *(int4*)&Asm[arow * 72 + asl * 8] = *(int4*)av;
        #pragma unroll
        for (int i = 0; i < 8; ++i) {
            int ch = t + i * 512;
            int row = ch >> 3, sl = ch & 7;
            *(int4*)&Bsm[row * 72 + sl * 8] = rbv[i];
        }
        __syncthreads();   // staging visible

        #pragma unroll
        for (int kk = 0; kk < 2; ++kk) {
            bf16x8 af[4], bfr[4];
            #pragma unroll
            for (int m = 0; m < 4; ++m)
                af[m] = *(const bf16x8*)&Asm[(m * 16 + l16) * 72 + kk * 32 + g8];
            #pragma unroll
            for (int n = 0; n < 4; ++n)
                bfr[n] = *(const bf16x8*)&Bsm[(wn * 64 + n * 16 + l16) * 72 + kk * 32 + g8];
            #pragma unroll
            for (int m = 0; m < 4; ++m)
                #pragma unroll
                for (int n = 0; n < 4; ++n)
                    acc[m][n] = __builtin_amdgcn_mfma_f32_16x16x32_bf16(
                        af[m], bfr[n], acc[m][n], 0, 0, 0);
        }
    }

    // bias
    float bv[4];
    #pragma unroll
    for (int n = 0; n < 4; ++n) bv[n] = b1[wn * 64 + n * 16 + l16];
    #pragma unroll
    for (int m = 0; m < 4; ++m)
        #pragma unroll
        for (int n = 0; n < 4; ++n)
            #pragma unroll
            for (int j = 0; j < 4; ++j) acc[m][n][j] += bv[n];

    // LN partials: per (m,j): sum over 4 n-frags, then over l16 (same row group)
    #pragma unroll
    for (int m = 0; m < 4; ++m)
        #pragma unroll
        for (int j = 0; j < 4; ++j) {
            float p = 0.f, q = 0.f;
            #pragma unroll
            for (int n = 0; n < 4; ++n) {
                float v = acc[m][n][j];
                p += v; q += v * v;
            }
            #pragma unroll
            for (int off = 8; off; off >>= 1) {
                p += __shfl_xor(p, off);
                q += __shfl_xor(q, off);
            }
            if (l16 == 0) {
                red[wn][m * 16 + g4 + j][0] = p;
                red[wn][m * 16 + g4 + j][1] = q;
            }
        }
    __syncthreads();
    if (t < 64) {
        float S = 0.f, S2 = 0.f;
        #pragma unroll
        for (int w = 0; w < 8; ++w) { S += red[w][t][0]; S2 += red[w][t][1]; }
        float mu  = S  * (1.f / NH1);
        float var = S2 * (1.f / NH1) - mu * mu;
        stats[t][0] = mu;
        stats[t][1] = rsqrtf(var + 1e-5f);
    }
    __syncthreads();

    float gv[4], ev[4];
    #pragma unroll
    for (int n = 0; n < 4; ++n) {
        int col = wn * 64 + n * 16 + l16;
        gv[n] = g1[col]; ev[n] = be1[col];
    }
    ushort* dst = h1 + (size_t)rb * NH1;
    #pragma unroll
    for (int m = 0; m < 4; ++m)
        #pragma unroll
        for (int j = 0; j < 4; ++j) {
            int row = m * 16 + g4 + j;
            float mu = stats[row][0], rs = stats[row][1];
            #pragma unroll
            for (int n = 0; n < 4; ++n) {
                float val = fmaxf(fmaf((acc[m][n][j] - mu) * rs, gv[n], ev[n]), 0.f);
                dst[(size_t)row * NH1 + wn * 64 + n * 16 + l16] = f2bf(val);
            }
        }
}

// ---------------------------------------------------------------------------
// k2: h2 = relu(LN(h1 @ W2 + b2)) ; h1 now bf16, h2 bf16
__global__ __launch_bounds__(256) void k_gemm_ln2(
    const ushort* __restrict__ h1, const float* __restrict__ W2,
    const float* __restrict__ b2, const float* __restrict__ g2,
    const float* __restrict__ be2, ushort* __restrict__ h2)
{
    __shared__ float hT[NH1][20];
    __shared__ float red[4][16][2];
    __shared__ float stats[16][2];
    const int t  = threadIdx.x;
    const int rb = blockIdx.x * 16;

    const ushort* src = h1 + (size_t)rb * NH1;
    #pragma unroll
    for (int k = 0; k < 32; ++k) {
        int idx = t + k * 256;
        hT[idx % NH1][idx / NH1] = bf2f(src[idx]);
    }
    __syncthreads();

    float acc[16];
    #pragma unroll
    for (int r = 0; r < 16; ++r) acc[r] = 0.f;

    for (int d = 0; d < NH1; ++d) {
        float w = W2[d * NH2 + t];
        float ev[16];
        *(float4*)&ev[0]  = *(const float4*)&hT[d][0];
        *(float4*)&ev[4]  = *(const float4*)&hT[d][4];
        *(float4*)&ev[8]  = *(const float4*)&hT[d][8];
        *(float4*)&ev[12] = *(const float4*)&hT[d][12];
        #pragma unroll
        for (int r = 0; r < 16; ++r) acc[r] = fmaf(ev[r], w, acc[r]);
    }
    const float bb = b2[t];
    #pragma unroll
    for (int r = 0; r < 16; ++r) acc[r] += bb;

    const int wid = t >> 6, lane = t & 63;
    #pragma unroll
    for (int r = 0; r < 16; ++r) {
        float p = acc[r];
        float q = acc[r] * acc[r];
        #pragma unroll
        for (int off = 32; off; off >>= 1) {
            p += __shfl_xor(p, off);
            q += __shfl_xor(q, off);
        }
        if (lane == 0) { red[wid][r][0] = p; red[wid][r][1] = q; }
    }
    __syncthreads();
    if (t < 16) {
        float S  = red[0][t][0] + red[1][t][0] + red[2][t][0] + red[3][t][0];
        float S2 = red[0][t][1] + red[1][t][1] + red[2][t][1] + red[3][t][1];
        float mu  = S  * (1.f / NH2);
        float var = S2 * (1.f / NH2) - mu * mu;
        stats[t][0] = mu;
        stats[t][1] = rsqrtf(var + 1e-5f);
    }
    __syncthreads();
    const float gg = g2[t], eb = be2[t];
    ushort* dst = h2 + (size_t)rb * NH2;
    #pragma unroll
    for (int r = 0; r < 16; ++r) {
        float mu = stats[r][0], rs = stats[r][1];
        dst[r * NH2 + t] = f2bf(fmaxf(fmaf((acc[r] - mu) * rs, gg, eb), 0.f));
    }
}

// ---------------------------------------------------------------------------
// k3a (MFMA): W_flat = h2 @ Wd + bd  (proven round-3 kernel, unchanged)
__global__ __launch_bounds__(256) void k_gemm_wd_mfma(
    const ushort* __restrict__ h2, const ushort* __restrict__ Wdt,
    const float* __restrict__ bd, float* __restrict__ wflat)
{
    __shared__ ushort Asm[128 * 72];
    __shared__ ushort Bsm[128 * 72];

    const int t    = threadIdx.x;
    const int lane = t & 63;
    const int wid  = t >> 6;
    const int wm   = wid >> 1;
    const int wn   = wid & 1;
    const int l16  = lane & 15;
    const int g8   = (lane >> 4) * 8;
    const int g4   = (lane >> 4) * 4;

    const int rb = blockIdx.y * 128;
    const int cb = blockIdx.x * 128;

    f32x4 acc[4][4] = {};

    for (int ks = 0; ks < 4; ++ks) {
        const int k0 = ks * 64;
        int4 ra[4], rbv[4];
        #pragma unroll
        for (int i = 0; i < 4; ++i) {
            int ch  = t + i * 256;
            int row = ch >> 3;
            int sl  = ch & 7;
            ra[i]  = *(const int4*)&h2 [(size_t)(rb + row) * NH2 + k0 + sl * 8];
            rbv[i] = *(const int4*)&Wdt[(size_t)(cb + row) * NH2 + k0 + sl * 8];
        }
        __syncthreads();
        #pragma unroll
        for (int i = 0; i < 4; ++i) {
            int ch  = t + i * 256;
            int row = ch >> 3;
            int sl  = ch & 7;
            *(int4*)&Asm[row * 72 + sl * 8] = ra[i];
            *(int4*)&Bsm[row * 72 + sl * 8] = rbv[i];
        }
        __syncthreads();

        #pragma unroll
        for (int kk = 0; kk < 2; ++kk) {
            bf16x8 af[4], bfr[4];
            #pragma unroll
            for (int m = 0; m < 4; ++m)
                af[m] = *(const bf16x8*)&Asm[(wm * 64 + m * 16 + l16) * 72 + kk * 32 + g8];
            #pragma unroll
            for (int n = 0; n < 4; ++n)
                bfr[n] = *(const bf16x8*)&Bsm[(wn * 64 + n * 16 + l16) * 72 + kk * 32 + g8];
            #pragma unroll
            for (int m = 0; m < 4; ++m)
                #pragma unroll
                for (int n = 0; n < 4; ++n)
                    acc[m][n] = __builtin_amdgcn_mfma_f32_16x16x32_bf16(
                        af[m], bfr[n], acc[m][n], 0, 0, 0);
        }
    }

    float bv[4];
    #pragma unroll
    for (int n = 0; n < 4; ++n)
        bv[n] = bd[cb + wn * 64 + n * 16 + l16];

    #pragma unroll
    for (int m = 0; m < 4; ++m) {
        const int row0 = rb + wm * 64 + m * 16 + g4;
        #pragma unroll
        for (int n = 0; n < 4; ++n) {
            const int col = cb + wn * 64 + n * 16 + l16;
            #pragma unroll
            for (int j = 0; j < 4; ++j)
                wflat[(size_t)(row0 + j) * ND + col] = acc[m][n][j] + bv[n];
        }
    }
}

// ---------------------------------------------------------------------------
// k3b: attn = softmax(h2 @ Wa + ba)  (h2 bf16)
__global__ __launch_bounds__(256) void k_attn(
    const ushort* __restrict__ h2, const float* __restrict__ Wa,
    const float* __restrict__ ba, float* __restrict__ attn)
{
    __shared__ float hT[NH2][20];
    __shared__ float red[4][16];
    __shared__ float stats[16];
    const int t  = threadIdx.x;
    const int rb = blockIdx.x * 16;

    const ushort* src = h2 + (size_t)rb * NH2;
    #pragma unroll
    for (int k = 0; k < 16; ++k) {
        int idx = t + k * 256;
        hT[idx % NH2][idx / NH2] = bf2f(src[idx]);
    }
    __syncthreads();

    float a0[16], a1[16], a2[16];
    #pragma unroll
    for (int r = 0; r < 16; ++r) { a0[r] = 0.f; a1[r] = 0.f; a2[r] = 0.f; }

    for (int d = 0; d < NH2; ++d) {
        float w0 = Wa[d * DD + t];
        float w1 = Wa[d * DD + t + 256];
        float w2 = Wa[d * DD + t + 512];
        float ev[16];
        *(float4*)&ev[0]  = *(const float4*)&hT[d][0];
        *(float4*)&ev[4]  = *(const float4*)&hT[d][4];
        *(float4*)&ev[8]  = *(const float4*)&hT[d][8];
        *(float4*)&ev[12] = *(const float4*)&hT[d][12];
        #pragma unroll
        for (int r = 0; r < 16; ++r) {
            a0[r] = fmaf(ev[r], w0, a0[r]);
            a1[r] = fmaf(ev[r], w1, a1[r]);
            a2[r] = fmaf(ev[r], w2, a2[r]);
        }
    }
    const float bb0 = ba[t], bb1 = ba[t + 256], bb2 = ba[t + 512];
    #pragma unroll
    for (int r = 0; r < 16; ++r) { a0[r] += bb0; a1[r] += bb1; a2[r] += bb2; }

    const int wid = t >> 6, lane = t & 63;
    #pragma unroll
    for (int r = 0; r < 16; ++r) {
        float m = fmaxf(a0[r], fmaxf(a1[r], a2[r]));
        #pragma unroll
        for (int off = 32; off; off >>= 1) m = fmaxf(m, __shfl_xor(m, off));
        if (lane == 0) red[wid][r] = m;
    }
    __syncthreads();
    if (t < 16)
        stats[t] = fmaxf(fmaxf(red[0][t], red[1][t]), fmaxf(red[2][t], red[3][t]));
    __syncthreads();
    #pragma unroll
    for (int r = 0; r < 16; ++r) {
        float M = stats[r];
        a0[r] = __expf(a0[r] - M);
        a1[r] = __expf(a1[r] - M);
        a2[r] = __expf(a2[r] - M);
    }
    #pragma unroll
    for (int r = 0; r < 16; ++r) {
        float s = a0[r] + a1[r] + a2[r];
        #pragma unroll
        for (int off = 32; off; off >>= 1) s += __shfl_xor(s, off);
        if (lane == 0) red[wid][r] = s;
    }
    __syncthreads();
    if (t < 16)
        stats[t] = 1.f / (red[0][t] + red[1][t] + red[2][t] + red[3][t]);
    __syncthreads();

    float* dst = attn + (size_t)rb * DD;
    #pragma unroll
    for (int r = 0; r < 16; ++r) {
        float inv = stats[r];
        dst[r * DD + t]       = a0[r] * inv;
        dst[r * DD + t + 256] = a1[r] * inv;
        dst[r * DD + t + 512] = a2[r] * inv;
    }
}

// ---------------------------------------------------------------------------
// k4: per row: W = W_flat.reshape(K,D) * attn; modified Gram-Schmidt; normalize.
__global__ __launch_bounds__(256) void k_gs(float* __restrict__ out)
{
    const int wid  = threadIdx.x >> 6;
    const int lane = threadIdx.x & 63;
    const size_t row = (size_t)blockIdx.x * 4 + wid;

    float* Wf = out + row * (KK * DD);
    const float* at = out + (size_t)BSZ * (KK * DD) + row * DD;

    float a[12];
    #pragma unroll
    for (int k = 0; k < 3; ++k) {
        float4 av = *(const float4*)&at[lane * 4 + 256 * k];
        a[k * 4 + 0] = av.x; a[k * 4 + 1] = av.y;
        a[k * 4 + 2] = av.z; a[k * 4 + 3] = av.w;
    }
    float w[4][12];
    #pragma unroll
    for (int i = 0; i < 4; ++i) {
        #pragma unroll
        for (int k = 0; k < 3; ++k) {
            float4 wv = *(const float4*)&Wf[i * DD + lane * 4 + 256 * k];
            w[i][k * 4 + 0] = wv.x * a[k * 4 + 0];
            w[i][k * 4 + 1] = wv.y * a[k * 4 + 1];
            w[i][k * 4 + 2] = wv.z * a[k * 4 + 2];
            w[i][k * 4 + 3] = wv.w * a[k * 4 + 3];
        }
    }
    #pragma unroll
    for (int i = 0; i < 4; ++i) {
        #pragma unroll
        for (int p = 0; p < i; ++p) {
            float s = 0.f;
            #pragma unroll
            for (int j = 0; j < 12; ++j) s = fmaf(w[i][j], w[p][j], s);
            #pragma unroll
            for (int off = 32; off; off >>= 1) s += __shfl_xor(s, off);
            #pragma unroll
            for (int j = 0; j < 12; ++j) w[i][j] = fmaf(-s, w[p][j], w[i][j]);
        }
        float n2 = 0.f;
        #pragma unroll
        for (int j = 0; j < 12; ++j) n2 = fmaf(w[i][j], w[i][j], n2);
        #pragma unroll
        for (int off = 32; off; off >>= 1) n2 += __shfl_xor(n2, off);
        float inv = 1.f / fmaxf(sqrtf(n2), 1e-12f);
        #pragma unroll
        for (int j = 0; j < 12; ++j) w[i][j] *= inv;
    }
    #pragma unroll
    for (int i = 0; i < 4; ++i) {
        #pragma unroll
        for (int k = 0; k < 3; ++k) {
            float4 wv;
            wv.x = w[i][k * 4 + 0]; wv.y = w[i][k * 4 + 1];
            wv.z = w[i][k * 4 + 2]; wv.w = w[i][k * 4 + 3];
            *(float4*)&Wf[i * DD + lane * 4 + 256 * k] = wv;
        }
    }
}

// ---------------------------------------------------------------------------
extern "C" void kernel_launch(void* const* d_in, const int* in_sizes, int n_in,
                              void* d_out, int out_size, void* d_ws, size_t ws_size,
                              hipStream_t stream)
{
    const float* emb = (const float*)d_in[0];
    const float* W1  = (const float*)d_in[1];
    const float* b1  = (const float*)d_in[2];
    const float* g1  = (const float*)d_in[3];
    const float* be1 = (const float*)d_in[4];
    const float* W2  = (const float*)d_in[5];
    const float* b2  = (const float*)d_in[6];
    const float* g2  = (const float*)d_in[7];
    const float* be2 = (const float*)d_in[8];
    const float* Wd  = (const float*)d_in[9];
    const float* bd  = (const float*)d_in[10];
    const float* Wa  = (const float*)d_in[11];
    const float* ba  = (const float*)d_in[12];

    float* out = (float*)d_out;
    ushort* h1  = (ushort*)d_ws;                 // B*512 bf16 = 16.8 MB
    ushort* h2  = h1 + (size_t)BSZ * NH1;        // B*256 bf16 =  8.4 MB
    ushort* Wdt = h2 + (size_t)BSZ * NH2;        // 3072*256 bf16 = 1.5 MB
    ushort* W1t = Wdt + (size_t)ND * NH2;        // 512*768 bf16 = 0.77 MB
    float* wfl  = out;                           // W region, B*K*D
    float* attn = out + (size_t)BSZ * KK * DD;   // attn region, B*D

    hipLaunchKernelGGL(k_t_cvt, dim3(NH1 / 32, DD / 32), dim3(256), 0, stream,
                       W1, W1t, DD, NH1);        // W1 (768x512) -> W1t (512x768)
    hipLaunchKernelGGL(k_t_cvt, dim3(ND / 32, NH2 / 32), dim3(256), 0, stream,
                       Wd, Wdt, NH2, ND);        // Wd (256x3072) -> Wdt (3072x256)
    hipLaunchKernelGGL(k1_mfma, dim3(BSZ / 64), dim3(512), 0, stream,
                       emb, W1t, b1, g1, be1, h1);
    hipLaunchKernelGGL(k_gemm_ln2, dim3(BSZ / 16), dim3(256), 0, stream,
                       h1, W2, b2, g2, be2, h2);
    hipLaunchKernelGGL(k_gemm_wd_mfma, dim3(ND / 128, BSZ / 128), dim3(256), 0, stream,
                       h2, Wdt, bd, wfl);
    hipLaunchKernelGGL(k_attn, dim3(BSZ / 16), dim3(256), 0, stream,
                       h2, Wa, ba, attn);
    hipLaunchKernelGGL(k_gs, dim3(BSZ / 4), dim3(256), 0, stream, out);
}

// Round 5
// 391.249 us; speedup vs baseline: 2.0678x; 1.2987x over previous
//
#include <hip/hip_runtime.h>
#include <hip/hip_bf16.h>

#define BSZ 16384
#define DD  768
#define KK  4
#define NH1 512
#define NH2 256
#define ND  (KK * DD)   // 3072

typedef __bf16 bf16x8 __attribute__((ext_vector_type(8)));
typedef float  f32x4  __attribute__((ext_vector_type(4)));

static __device__ __forceinline__ float bf2f(ushort u) {
    union { unsigned int i; float f; } v; v.i = (unsigned int)u << 16; return v.f;
}
static __device__ __forceinline__ ushort f2bf(float f) {
    return __bfloat16_as_ushort(__float2bfloat16(f));
}

// ---------------------------------------------------------------------------
// k_t_cvt: src (R x C f32) -> dst (C x R bf16)  [generic transpose+convert]
__global__ __launch_bounds__(256) void k_t_cvt(
    const float* __restrict__ src, ushort* __restrict__ dst, int R, int C)
{
    __shared__ float tile[32][33];
    const int rb0 = blockIdx.y * 32;  // src row
    const int cb0 = blockIdx.x * 32;  // src col
    const int t = threadIdx.x;
    const int r = t >> 5, c = t & 31;
    #pragma unroll
    for (int i = 0; i < 4; ++i)
        tile[r + i * 8][c] = src[(size_t)(rb0 + r + i * 8) * C + cb0 + c];
    __syncthreads();
    #pragma unroll
    for (int i = 0; i < 4; ++i)
        dst[(size_t)(cb0 + r + i * 8) * R + rb0 + c] = f2bf(tile[c][r + i * 8]);
}

// ---------------------------------------------------------------------------
// k1 (MFMA, fused LN+relu): h1 = relu(LN(emb @ W1 + b1)) stored bf16
__global__ __launch_bounds__(512) void k1_mfma(
    const float* __restrict__ emb, const ushort* __restrict__ W1t,
    const float* __restrict__ b1, const float* __restrict__ g1,
    const float* __restrict__ be1, ushort* __restrict__ h1)
{
    __shared__ ushort Asm[64 * 72];    //  9.2 KB
    __shared__ ushort Bsm[512 * 72];   // 73.7 KB
    __shared__ float red[8][64][2];    //  4 KB
    __shared__ float stats[64][2];

    const int t    = threadIdx.x;
    const int lane = t & 63;
    const int wn   = t >> 6;            // 0..7
    const int l16  = lane & 15;
    const int g8   = (lane >> 4) * 8;
    const int g4   = (lane >> 4) * 4;
    const int rb   = blockIdx.x * 64;

    const int arow = t >> 3, asl = t & 7;   // A: 512 chunks, 1/thread

    f32x4 acc[4][4] = {};

    for (int ks = 0; ks < 12; ++ks) {
        const int k0 = ks * 64;
        float4 a0 = *(const float4*)&emb[(size_t)(rb + arow) * DD + k0 + asl * 8];
        float4 a1 = *(const float4*)&emb[(size_t)(rb + arow) * DD + k0 + asl * 8 + 4];
        int4 rbv[8];
        #pragma unroll
        for (int i = 0; i < 8; ++i) {
            int ch = t + i * 512;           // B: 4096 chunks, 8/thread
            int row = ch >> 3, sl = ch & 7;
            rbv[i] = *(const int4*)&W1t[(size_t)row * DD + k0 + sl * 8];
        }
        __syncthreads();   // prev-tile reads done
        ushort av[8];
        av[0] = f2bf(a0.x); av[1] = f2bf(a0.y); av[2] = f2bf(a0.z); av[3] = f2bf(a0.w);
        av[4] = f2bf(a1.x); av[5] = f2bf(a1.y); av[6] = f2bf(a1.z); av[7] = f2bf(a1.w);
        *(int4*)&Asm[arow * 72 + asl * 8] = *(int4*)av;
        #pragma unroll
        for (int i = 0; i < 8; ++i) {
            int ch = t + i * 512;
            int row = ch >> 3, sl = ch & 7;
            *(int4*)&Bsm[row * 72 + sl * 8] = rbv[i];
        }
        __syncthreads();   // staging visible

        #pragma unroll
        for (int kk = 0; kk < 2; ++kk) {
            bf16x8 af[4], bfr[4];
            #pragma unroll
            for (int m = 0; m < 4; ++m)
                af[m] = *(const bf16x8*)&Asm[(m * 16 + l16) * 72 + kk * 32 + g8];
            #pragma unroll
            for (int n = 0; n < 4; ++n)
                bfr[n] = *(const bf16x8*)&Bsm[(wn * 64 + n * 16 + l16) * 72 + kk * 32 + g8];
            #pragma unroll
            for (int m = 0; m < 4; ++m)
                #pragma unroll
                for (int n = 0; n < 4; ++n)
                    acc[m][n] = __builtin_amdgcn_mfma_f32_16x16x32_bf16(
                        af[m], bfr[n], acc[m][n], 0, 0, 0);
        }
    }

    float bv[4];
    #pragma unroll
    for (int n = 0; n < 4; ++n) bv[n] = b1[wn * 64 + n * 16 + l16];
    #pragma unroll
    for (int m = 0; m < 4; ++m)
        #pragma unroll
        for (int n = 0; n < 4; ++n)
            #pragma unroll
            for (int j = 0; j < 4; ++j) acc[m][n][j] += bv[n];

    #pragma unroll
    for (int m = 0; m < 4; ++m)
        #pragma unroll
        for (int j = 0; j < 4; ++j) {
            float p = 0.f, q = 0.f;
            #pragma unroll
            for (int n = 0; n < 4; ++n) {
                float v = acc[m][n][j];
                p += v; q += v * v;
            }
            #pragma unroll
            for (int off = 8; off; off >>= 1) {
                p += __shfl_xor(p, off);
                q += __shfl_xor(q, off);
            }
            if (l16 == 0) {
                red[wn][m * 16 + g4 + j][0] = p;
                red[wn][m * 16 + g4 + j][1] = q;
            }
        }
    __syncthreads();
    if (t < 64) {
        float S = 0.f, S2 = 0.f;
        #pragma unroll
        for (int w = 0; w < 8; ++w) { S += red[w][t][0]; S2 += red[w][t][1]; }
        float mu  = S  * (1.f / NH1);
        float var = S2 * (1.f / NH1) - mu * mu;
        stats[t][0] = mu;
        stats[t][1] = rsqrtf(var + 1e-5f);
    }
    __syncthreads();

    float gv[4], ev[4];
    #pragma unroll
    for (int n = 0; n < 4; ++n) {
        int col = wn * 64 + n * 16 + l16;
        gv[n] = g1[col]; ev[n] = be1[col];
    }
    ushort* dst = h1 + (size_t)rb * NH1;
    #pragma unroll
    for (int m = 0; m < 4; ++m)
        #pragma unroll
        for (int j = 0; j < 4; ++j) {
            int row = m * 16 + g4 + j;
            float mu = stats[row][0], rs = stats[row][1];
            #pragma unroll
            for (int n = 0; n < 4; ++n) {
                float val = fmaxf(fmaf((acc[m][n][j] - mu) * rs, gv[n], ev[n]), 0.f);
                dst[(size_t)row * NH1 + wn * 64 + n * 16 + l16] = f2bf(val);
            }
        }
}

// ---------------------------------------------------------------------------
// k2 (MFMA, fused LN+relu): h2 = relu(LN(h1 @ W2 + b2)) stored bf16
// Tile 64 x 256 (full N), BK=64, 8 K-steps. 512 thr = 8 waves (2m x 4n),
// wave tile 32 x 64 (2x4 frags). W2t pre-transposed bf16 (256 x 512).
__global__ __launch_bounds__(512) void k2_mfma(
    const ushort* __restrict__ h1, const ushort* __restrict__ W2t,
    const float* __restrict__ b2, const float* __restrict__ g2,
    const float* __restrict__ be2, ushort* __restrict__ h2)
{
    __shared__ ushort Asm[64 * 72];     //  9.2 KB
    __shared__ ushort Bsm[256 * 72];    // 36.9 KB
    __shared__ float red[8][64][2];
    __shared__ float stats[64][2];

    const int t    = threadIdx.x;
    const int lane = t & 63;
    const int wid  = t >> 6;
    const int wm   = wid >> 2;          // 0..1
    const int wn   = wid & 3;           // 0..3
    const int l16  = lane & 15;
    const int g8   = (lane >> 4) * 8;
    const int g4   = (lane >> 4) * 4;
    const int rb   = blockIdx.x * 64;

    const int arow = t >> 3, asl = t & 7;   // A: 512 chunks, 1/thread

    f32x4 acc[2][4] = {};

    for (int ks = 0; ks < 8; ++ks) {
        const int k0 = ks * 64;
        int4 ra = *(const int4*)&h1[(size_t)(rb + arow) * NH1 + k0 + asl * 8];
        int4 rbv[4];
        #pragma unroll
        for (int i = 0; i < 4; ++i) {
            int ch = t + i * 512;           // B: 2048 chunks, 4/thread
            int row = ch >> 3, sl = ch & 7;
            rbv[i] = *(const int4*)&W2t[(size_t)row * NH1 + k0 + sl * 8];
        }
        __syncthreads();
        *(int4*)&Asm[arow * 72 + asl * 8] = ra;
        #pragma unroll
        for (int i = 0; i < 4; ++i) {
            int ch = t + i * 512;
            int row = ch >> 3, sl = ch & 7;
            *(int4*)&Bsm[row * 72 + sl * 8] = rbv[i];
        }
        __syncthreads();

        #pragma unroll
        for (int kk = 0; kk < 2; ++kk) {
            bf16x8 af[2], bfr[4];
            #pragma unroll
            for (int m = 0; m < 2; ++m)
                af[m] = *(const bf16x8*)&Asm[(wm * 32 + m * 16 + l16) * 72 + kk * 32 + g8];
            #pragma unroll
            for (int n = 0; n < 4; ++n)
                bfr[n] = *(const bf16x8*)&Bsm[(wn * 64 + n * 16 + l16) * 72 + kk * 32 + g8];
            #pragma unroll
            for (int m = 0; m < 2; ++m)
                #pragma unroll
                for (int n = 0; n < 4; ++n)
                    acc[m][n] = __builtin_amdgcn_mfma_f32_16x16x32_bf16(
                        af[m], bfr[n], acc[m][n], 0, 0, 0);
        }
    }

    float bv[4];
    #pragma unroll
    for (int n = 0; n < 4; ++n) bv[n] = b2[wn * 64 + n * 16 + l16];
    #pragma unroll
    for (int m = 0; m < 2; ++m)
        #pragma unroll
        for (int n = 0; n < 4; ++n)
            #pragma unroll
            for (int j = 0; j < 4; ++j) acc[m][n][j] += bv[n];

    // LN partials: row = wm*32 + m*16 + g4 + j
    #pragma unroll
    for (int m = 0; m < 2; ++m)
        #pragma unroll
        for (int j = 0; j < 4; ++j) {
            float p = 0.f, q = 0.f;
            #pragma unroll
            for (int n = 0; n < 4; ++n) {
                float v = acc[m][n][j];
                p += v; q += v * v;
            }
            #pragma unroll
            for (int off = 8; off; off >>= 1) {
                p += __shfl_xor(p, off);
                q += __shfl_xor(q, off);
            }
            if (l16 == 0) {
                red[wid][wm * 32 + m * 16 + g4 + j][0] = p;
                red[wid][wm * 32 + m * 16 + g4 + j][1] = q;
            }
        }
    __syncthreads();
    if (t < 64) {
        const int w0 = (t >> 5) * 4;    // waves sharing this row half
        float S = 0.f, S2 = 0.f;
        #pragma unroll
        for (int w = 0; w < 4; ++w) { S += red[w0 + w][t][0]; S2 += red[w0 + w][t][1]; }
        float mu  = S  * (1.f / NH2);
        float var = S2 * (1.f / NH2) - mu * mu;
        stats[t][0] = mu;
        stats[t][1] = rsqrtf(var + 1e-5f);
    }
    __syncthreads();

    float gv[4], ev[4];
    #pragma unroll
    for (int n = 0; n < 4; ++n) {
        int col = wn * 64 + n * 16 + l16;
        gv[n] = g2[col]; ev[n] = be2[col];
    }
    ushort* dst = h2 + (size_t)rb * NH2;
    #pragma unroll
    for (int m = 0; m < 2; ++m)
        #pragma unroll
        for (int j = 0; j < 4; ++j) {
            int row = wm * 32 + m * 16 + g4 + j;
            float mu = stats[row][0], rs = stats[row][1];
            #pragma unroll
            for (int n = 0; n < 4; ++n) {
                float val = fmaxf(fmaf((acc[m][n][j] - mu) * rs, gv[n], ev[n]), 0.f);
                dst[(size_t)row * NH2 + wn * 64 + n * 16 + l16] = f2bf(val);
            }
        }
}

// ---------------------------------------------------------------------------
// k3a (MFMA): W_flat(bf16) = h2 @ Wd + bd, packed into the SECOND half of each
// output row's fp32 slot (row*12288B + 6144B). Epilogue staged through LDS for
// full-line coalesced stores (round-4 scattered dwords showed 3x write ampl.).
__global__ __launch_bounds__(256) void k_gemm_wd_mfma(
    const ushort* __restrict__ h2, const ushort* __restrict__ Wdt,
    const float* __restrict__ bd, ushort* __restrict__ outw)
{
    __shared__ ushort smem[2 * 128 * 72];   // Asm | Bsm; reused for C-stage
    ushort* Asm = smem;
    ushort* Bsm = smem + 128 * 72;

    const int t    = threadIdx.x;
    const int lane = t & 63;
    const int wid  = t >> 6;
    const int wm   = wid >> 1;
    const int wn   = wid & 1;
    const int l16  = lane & 15;
    const int g8   = (lane >> 4) * 8;
    const int g4   = (lane >> 4) * 4;

    const int rb = blockIdx.y * 128;
    const int cb = blockIdx.x * 128;

    f32x4 acc[4][4] = {};

    for (int ks = 0; ks < 4; ++ks) {
        const int k0 = ks * 64;
        int4 ra[4], rbv[4];
        #pragma unroll
        for (int i = 0; i < 4; ++i) {
            int ch  = t + i * 256;
            int row = ch >> 3;
            int sl  = ch & 7;
            ra[i]  = *(const int4*)&h2 [(size_t)(rb + row) * NH2 + k0 + sl * 8];
            rbv[i] = *(const int4*)&Wdt[(size_t)(cb + row) * NH2 + k0 + sl * 8];
        }
        __syncthreads();
        #pragma unroll
        for (int i = 0; i < 4; ++i) {
            int ch  = t + i * 256;
            int row = ch >> 3;
            int sl  = ch & 7;
            *(int4*)&Asm[row * 72 + sl * 8] = ra[i];
            *(int4*)&Bsm[row * 72 + sl * 8] = rbv[i];
        }
        __syncthreads();

        #pragma unroll
        for (int kk = 0; kk < 2; ++kk) {
            bf16x8 af[4], bfr[4];
            #pragma unroll
            for (int m = 0; m < 4; ++m)
                af[m] = *(const bf16x8*)&Asm[(wm * 64 + m * 16 + l16) * 72 + kk * 32 + g8];
            #pragma unroll
            for (int n = 0; n < 4; ++n)
                bfr[n] = *(const bf16x8*)&Bsm[(wn * 64 + n * 16 + l16) * 72 + kk * 32 + g8];
            #pragma unroll
            for (int m = 0; m < 4; ++m)
                #pragma unroll
                for (int n = 0; n < 4; ++n)
                    acc[m][n] = __builtin_amdgcn_mfma_f32_16x16x32_bf16(
                        af[m], bfr[n], acc[m][n], 0, 0, 0);
        }
    }

    float bv[4];
    #pragma unroll
    for (int n = 0; n < 4; ++n)
        bv[n] = bd[cb + wn * 64 + n * 16 + l16];

    __syncthreads();   // all waves done reading K-loop LDS
    // stage C tile (128x128 bf16 = 32 KB) into smem
    #pragma unroll
    for (int m = 0; m < 4; ++m)
        #pragma unroll
        for (int n = 0; n < 4; ++n)
            #pragma unroll
            for (int j = 0; j < 4; ++j)
                smem[(wm * 64 + m * 16 + g4 + j) * 128 + wn * 64 + n * 16 + l16] =
                    f2bf(acc[m][n][j] + bv[n]);
    __syncthreads();
    // coalesced write: 128 rows x 256 B
    #pragma unroll
    for (int i = 0; i < 8; ++i) {
        int ch  = t + i * 256;          // 2048 chunks of 16 B
        int row = ch >> 4;
        int q   = ch & 15;
        *(int4*)&outw[(size_t)(rb + row) * 6144 + 3072 + cb + q * 8] =
            *(const int4*)&smem[row * 128 + q * 8];
    }
}

// ---------------------------------------------------------------------------
// k3b: attn = softmax(h2 @ Wa + ba)  (h2 bf16)
__global__ __launch_bounds__(256) void k_attn(
    const ushort* __restrict__ h2, const float* __restrict__ Wa,
    const float* __restrict__ ba, float* __restrict__ attn)
{
    __shared__ float hT[NH2][20];
    __shared__ float red[4][16];
    __shared__ float stats[16];
    const int t  = threadIdx.x;
    const int rb = blockIdx.x * 16;

    const ushort* src = h2 + (size_t)rb * NH2;
    #pragma unroll
    for (int k = 0; k < 16; ++k) {
        int idx = t + k * 256;
        hT[idx % NH2][idx / NH2] = bf2f(src[idx]);
    }
    __syncthreads();

    float a0[16], a1[16], a2[16];
    #pragma unroll
    for (int r = 0; r < 16; ++r) { a0[r] = 0.f; a1[r] = 0.f; a2[r] = 0.f; }

    for (int d = 0; d < NH2; ++d) {
        float w0 = Wa[d * DD + t];
        float w1 = Wa[d * DD + t + 256];
        float w2 = Wa[d * DD + t + 512];
        float ev[16];
        *(float4*)&ev[0]  = *(const float4*)&hT[d][0];
        *(float4*)&ev[4]  = *(const float4*)&hT[d][4];
        *(float4*)&ev[8]  = *(const float4*)&hT[d][8];
        *(float4*)&ev[12] = *(const float4*)&hT[d][12];
        #pragma unroll
        for (int r = 0; r < 16; ++r) {
            a0[r] = fmaf(ev[r], w0, a0[r]);
            a1[r] = fmaf(ev[r], w1, a1[r]);
            a2[r] = fmaf(ev[r], w2, a2[r]);
        }
    }
    const float bb0 = ba[t], bb1 = ba[t + 256], bb2 = ba[t + 512];
    #pragma unroll
    for (int r = 0; r < 16; ++r) { a0[r] += bb0; a1[r] += bb1; a2[r] += bb2; }

    const int wid = t >> 6, lane = t & 63;
    #pragma unroll
    for (int r = 0; r < 16; ++r) {
        float m = fmaxf(a0[r], fmaxf(a1[r], a2[r]));
        #pragma unroll
        for (int off = 32; off; off >>= 1) m = fmaxf(m, __shfl_xor(m, off));
        if (lane == 0) red[wid][r] = m;
    }
    __syncthreads();
    if (t < 16)
        stats[t] = fmaxf(fmaxf(red[0][t], red[1][t]), fmaxf(red[2][t], red[3][t]));
    __syncthreads();
    #pragma unroll
    for (int r = 0; r < 16; ++r) {
        float M = stats[r];
        a0[r] = __expf(a0[r] - M);
        a1[r] = __expf(a1[r] - M);
        a2[r] = __expf(a2[r] - M);
    }
    #pragma unroll
    for (int r = 0; r < 16; ++r) {
        float s = a0[r] + a1[r] + a2[r];
        #pragma unroll
        for (int off = 32; off; off >>= 1) s += __shfl_xor(s, off);
        if (lane == 0) red[wid][r] = s;
    }
    __syncthreads();
    if (t < 16)
        stats[t] = 1.f / (red[0][t] + red[1][t] + red[2][t] + red[3][t]);
    __syncthreads();

    float* dst = attn + (size_t)rb * DD;
    #pragma unroll
    for (int r = 0; r < 16; ++r) {
        float inv = stats[r];
        dst[r * DD + t]       = a0[r] * inv;
        dst[r * DD + t + 256] = a1[r] * inv;
        dst[r * DD + t + 512] = a2[r] * inv;
    }
}

// ---------------------------------------------------------------------------
// k4: per row: W = Wflat_bf16 * attn; modified Gram-Schmidt; normalize.
// Reads bf16 W from second half of own row slot, writes fp32 over full slot.
__global__ __launch_bounds__(256) void k_gs(float* __restrict__ out)
{
    const int wid  = threadIdx.x >> 6;
    const int lane = threadIdx.x & 63;
    const size_t row = (size_t)blockIdx.x * 4 + wid;

    float* Wf = out + row * (KK * DD);
    const ushort* wsrc = (const ushort*)out + row * 6144 + 3072;
    const float* at = out + (size_t)BSZ * (KK * DD) + row * DD;

    float a[12];
    #pragma unroll
    for (int k = 0; k < 3; ++k) {
        float4 av = *(const float4*)&at[lane * 4 + 256 * k];
        a[k * 4 + 0] = av.x; a[k * 4 + 1] = av.y;
        a[k * 4 + 2] = av.z; a[k * 4 + 3] = av.w;
    }
    float w[4][12];
    #pragma unroll
    for (int i = 0; i < 4; ++i) {
        #pragma unroll
        for (int k = 0; k < 3; ++k) {
            ushort4 uv = *(const ushort4*)&wsrc[i * DD + lane * 4 + 256 * k];
            w[i][k * 4 + 0] = bf2f(uv.x) * a[k * 4 + 0];
            w[i][k * 4 + 1] = bf2f(uv.y) * a[k * 4 + 1];
            w[i][k * 4 + 2] = bf2f(uv.z) * a[k * 4 + 2];
            w[i][k * 4 + 3] = bf2f(uv.w) * a[k * 4 + 3];
        }
    }
    #pragma unroll
    for (int i = 0; i < 4; ++i) {
        #pragma unroll
        for (int p = 0; p < i; ++p) {
            float s = 0.f;
            #pragma unroll
            for (int j = 0; j < 12; ++j) s = fmaf(w[i][j], w[p][j], s);
            #pragma unroll
            for (int off = 32; off; off >>= 1) s += __shfl_xor(s, off);
            #pragma unroll
            for (int j = 0; j < 12; ++j) w[i][j] = fmaf(-s, w[p][j], w[i][j]);
        }
        float n2 = 0.f;
        #pragma unroll
        for (int j = 0; j < 12; ++j) n2 = fmaf(w[i][j], w[i][j], n2);
        #pragma unroll
        for (int off = 32; off; off >>= 1) n2 += __shfl_xor(n2, off);
        float inv = 1.f / fmaxf(sqrtf(n2), 1e-12f);
        #pragma unroll
        for (int j = 0; j < 12; ++j) w[i][j] *= inv;
    }
    #pragma unroll
    for (int i = 0; i < 4; ++i) {
        #pragma unroll
        for (int k = 0; k < 3; ++k) {
            float4 wv;
            wv.x = w[i][k * 4 + 0]; wv.y = w[i][k * 4 + 1];
            wv.z = w[i][k * 4 + 2]; wv.w = w[i][k * 4 + 3];
            *(float4*)&Wf[i * DD + lane * 4 + 256 * k] = wv;
        }
    }
}

// ---------------------------------------------------------------------------
extern "C" void kernel_launch(void* const* d_in, const int* in_sizes, int n_in,
                              void* d_out, int out_size, void* d_ws, size_t ws_size,
                              hipStream_t stream)
{
    const float* emb = (const float*)d_in[0];
    const float* W1  = (const float*)d_in[1];
    const float* b1  = (const float*)d_in[2];
    const float* g1  = (const float*)d_in[3];
    const float* be1 = (const float*)d_in[4];
    const float* W2  = (const float*)d_in[5];
    const float* b2  = (const float*)d_in[6];
    const float* g2  = (const float*)d_in[7];
    const float* be2 = (const float*)d_in[8];
    const float* Wd  = (const float*)d_in[9];
    const float* bd  = (const float*)d_in[10];
    const float* Wa  = (const float*)d_in[11];
    const float* ba  = (const float*)d_in[12];

    float* out = (float*)d_out;
    ushort* h1  = (ushort*)d_ws;                 // B*512 bf16 = 16.8 MB
    ushort* h2  = h1 + (size_t)BSZ * NH1;        // B*256 bf16 =  8.4 MB
    ushort* Wdt = h2 + (size_t)BSZ * NH2;        // 3072*256 bf16 = 1.5 MB
    ushort* W1t = Wdt + (size_t)ND * NH2;        // 512*768 bf16 = 0.77 MB
    ushort* W2t = W1t + (size_t)NH1 * DD;        // 256*512 bf16 = 0.25 MB
    float* attn = out + (size_t)BSZ * KK * DD;   // attn region, B*D

    hipLaunchKernelGGL(k_t_cvt, dim3(NH1 / 32, DD / 32), dim3(256), 0, stream,
                       W1, W1t, DD, NH1);        // W1 (768x512) -> W1t (512x768)
    hipLaunchKernelGGL(k_t_cvt, dim3(NH2 / 32, NH1 / 32), dim3(256), 0, stream,
                       W2, W2t, NH1, NH2);       // W2 (512x256) -> W2t (256x512)
    hipLaunchKernelGGL(k_t_cvt, dim3(ND / 32, NH2 / 32), dim3(256), 0, stream,
                       Wd, Wdt, NH2, ND);        // Wd (256x3072) -> Wdt (3072x256)
    hipLaunchKernelGGL(k1_mfma, dim3(BSZ / 64), dim3(512), 0, stream,
                       emb, W1t, b1, g1, be1, h1);
    hipLaunchKernelGGL(k2_mfma, dim3(BSZ / 64), dim3(512), 0, stream,
                       h1, W2t, b2, g2, be2, h2);
    hipLaunchKernelGGL(k_gemm_wd_mfma, dim3(ND / 128, BSZ / 128), dim3(256), 0, stream,
                       h2, Wdt, bd, (ushort*)out);
    hipLaunchKernelGGL(k_attn, dim3(BSZ / 16), dim3(256), 0, stream,
                       h2, Wa, ba, attn);
    hipLaunchKernelGGL(k_gs, dim3(BSZ / 4), dim3(256), 0, stream, out);
}

// Round 6
// 351.723 us; speedup vs baseline: 2.3002x; 1.1124x over previous
//
#include <hip/hip_runtime.h>
#include <hip/hip_bf16.h>

#define BSZ 16384
#define DD  768
#define KK  4
#define NH1 512
#define NH2 256
#define ND  (KK * DD)   // 3072

typedef __bf16 bf16x8 __attribute__((ext_vector_type(8)));
typedef float  f32x4  __attribute__((ext_vector_type(4)));

static __device__ __forceinline__ float bf2f(ushort u) {
    union { unsigned int i; float f; } v; v.i = (unsigned int)u << 16; return v.f;
}
static __device__ __forceinline__ ushort f2bf(float f) {
    return __bfloat16_as_ushort(__float2bfloat16(f));
}

// ---------------------------------------------------------------------------
// k_t_cvt: src (R x C f32) -> dst (C x R bf16)  [generic transpose+convert]
__global__ __launch_bounds__(256) void k_t_cvt(
    const float* __restrict__ src, ushort* __restrict__ dst, int R, int C)
{
    __shared__ float tile[32][33];
    const int rb0 = blockIdx.y * 32;  // src row
    const int cb0 = blockIdx.x * 32;  // src col
    const int t = threadIdx.x;
    const int r = t >> 5, c = t & 31;
    #pragma unroll
    for (int i = 0; i < 4; ++i)
        tile[r + i * 8][c] = src[(size_t)(rb0 + r + i * 8) * C + cb0 + c];
    __syncthreads();
    #pragma unroll
    for (int i = 0; i < 4; ++i)
        dst[(size_t)(cb0 + r + i * 8) * R + rb0 + c] = f2bf(tile[c][r + i * 8]);
}

// ---------------------------------------------------------------------------
// k1 (MFMA, fused LN+relu): h1 = relu(LN(emb @ W1 + b1)) stored bf16
__global__ __launch_bounds__(512) void k1_mfma(
    const float* __restrict__ emb, const ushort* __restrict__ W1t,
    const float* __restrict__ b1, const float* __restrict__ g1,
    const float* __restrict__ be1, ushort* __restrict__ h1)
{
    __shared__ ushort Asm[64 * 72];    //  9.2 KB
    __shared__ ushort Bsm[512 * 72];   // 73.7 KB
    __shared__ float red[8][64][2];    //  4 KB
    __shared__ float stats[64][2];

    const int t    = threadIdx.x;
    const int lane = t & 63;
    const int wn   = t >> 6;            // 0..7
    const int l16  = lane & 15;
    const int g8   = (lane >> 4) * 8;
    const int g4   = (lane >> 4) * 4;
    const int rb   = blockIdx.x * 64;

    const int arow = t >> 3, asl = t & 7;   // A: 512 chunks, 1/thread

    f32x4 acc[4][4] = {};

    for (int ks = 0; ks < 12; ++ks) {
        const int k0 = ks * 64;
        float4 a0 = *(const float4*)&emb[(size_t)(rb + arow) * DD + k0 + asl * 8];
        float4 a1 = *(const float4*)&emb[(size_t)(rb + arow) * DD + k0 + asl * 8 + 4];
        int4 rbv[8];
        #pragma unroll
        for (int i = 0; i < 8; ++i) {
            int ch = t + i * 512;           // B: 4096 chunks, 8/thread
            int row = ch >> 3, sl = ch & 7;
            rbv[i] = *(const int4*)&W1t[(size_t)row * DD + k0 + sl * 8];
        }
        __syncthreads();   // prev-tile reads done
        ushort av[8];
        av[0] = f2bf(a0.x); av[1] = f2bf(a0.y); av[2] = f2bf(a0.z); av[3] = f2bf(a0.w);
        av[4] = f2bf(a1.x); av[5] = f2bf(a1.y); av[6] = f2bf(a1.z); av[7] = f2bf(a1.w);
        *(int4*)&Asm[arow * 72 + asl * 8] = *(int4*)av;
        #pragma unroll
        for (int i = 0; i < 8; ++i) {
            int ch = t + i * 512;
            int row = ch >> 3, sl = ch & 7;
            *(int4*)&Bsm[row * 72 + sl * 8] = rbv[i];
        }
        __syncthreads();   // staging visible

        #pragma unroll
        for (int kk = 0; kk < 2; ++kk) {
            bf16x8 af[4], bfr[4];
            #pragma unroll
            for (int m = 0; m < 4; ++m)
                af[m] = *(const bf16x8*)&Asm[(m * 16 + l16) * 72 + kk * 32 + g8];
            #pragma unroll
            for (int n = 0; n < 4; ++n)
                bfr[n] = *(const bf16x8*)&Bsm[(wn * 64 + n * 16 + l16) * 72 + kk * 32 + g8];
            #pragma unroll
            for (int m = 0; m < 4; ++m)
                #pragma unroll
                for (int n = 0; n < 4; ++n)
                    acc[m][n] = __builtin_amdgcn_mfma_f32_16x16x32_bf16(
                        af[m], bfr[n], acc[m][n], 0, 0, 0);
        }
    }

    float bv[4];
    #pragma unroll
    for (int n = 0; n < 4; ++n) bv[n] = b1[wn * 64 + n * 16 + l16];
    #pragma unroll
    for (int m = 0; m < 4; ++m)
        #pragma unroll
        for (int n = 0; n < 4; ++n)
            #pragma unroll
            for (int j = 0; j < 4; ++j) acc[m][n][j] += bv[n];

    #pragma unroll
    for (int m = 0; m < 4; ++m)
        #pragma unroll
        for (int j = 0; j < 4; ++j) {
            float p = 0.f, q = 0.f;
            #pragma unroll
            for (int n = 0; n < 4; ++n) {
                float v = acc[m][n][j];
                p += v; q += v * v;
            }
            #pragma unroll
            for (int off = 8; off; off >>= 1) {
                p += __shfl_xor(p, off);
                q += __shfl_xor(q, off);
            }
            if (l16 == 0) {
                red[wn][m * 16 + g4 + j][0] = p;
                red[wn][m * 16 + g4 + j][1] = q;
            }
        }
    __syncthreads();
    if (t < 64) {
        float S = 0.f, S2 = 0.f;
        #pragma unroll
        for (int w = 0; w < 8; ++w) { S += red[w][t][0]; S2 += red[w][t][1]; }
        float mu  = S  * (1.f / NH1);
        float var = S2 * (1.f / NH1) - mu * mu;
        stats[t][0] = mu;
        stats[t][1] = rsqrtf(var + 1e-5f);
    }
    __syncthreads();

    float gv[4], ev[4];
    #pragma unroll
    for (int n = 0; n < 4; ++n) {
        int col = wn * 64 + n * 16 + l16;
        gv[n] = g1[col]; ev[n] = be1[col];
    }
    ushort* dst = h1 + (size_t)rb * NH1;
    #pragma unroll
    for (int m = 0; m < 4; ++m)
        #pragma unroll
        for (int j = 0; j < 4; ++j) {
            int row = m * 16 + g4 + j;
            float mu = stats[row][0], rs = stats[row][1];
            #pragma unroll
            for (int n = 0; n < 4; ++n) {
                float val = fmaxf(fmaf((acc[m][n][j] - mu) * rs, gv[n], ev[n]), 0.f);
                dst[(size_t)row * NH1 + wn * 64 + n * 16 + l16] = f2bf(val);
            }
        }
}

// ---------------------------------------------------------------------------
// k2 (MFMA, fused LN+relu): h2 = relu(LN(h1 @ W2 + b2)) stored bf16
__global__ __launch_bounds__(512) void k2_mfma(
    const ushort* __restrict__ h1, const ushort* __restrict__ W2t,
    const float* __restrict__ b2, const float* __restrict__ g2,
    const float* __restrict__ be2, ushort* __restrict__ h2)
{
    __shared__ ushort Asm[64 * 72];     //  9.2 KB
    __shared__ ushort Bsm[256 * 72];    // 36.9 KB
    __shared__ float red[8][64][2];
    __shared__ float stats[64][2];

    const int t    = threadIdx.x;
    const int lane = t & 63;
    const int wid  = t >> 6;
    const int wm   = wid >> 2;          // 0..1
    const int wn   = wid & 3;           // 0..3
    const int l16  = lane & 15;
    const int g8   = (lane >> 4) * 8;
    const int g4   = (lane >> 4) * 4;
    const int rb   = blockIdx.x * 64;

    const int arow = t >> 3, asl = t & 7;   // A: 512 chunks, 1/thread

    f32x4 acc[2][4] = {};

    for (int ks = 0; ks < 8; ++ks) {
        const int k0 = ks * 64;
        int4 ra = *(const int4*)&h1[(size_t)(rb + arow) * NH1 + k0 + asl * 8];
        int4 rbv[4];
        #pragma unroll
        for (int i = 0; i < 4; ++i) {
            int ch = t + i * 512;           // B: 2048 chunks, 4/thread
            int row = ch >> 3, sl = ch & 7;
            rbv[i] = *(const int4*)&W2t[(size_t)row * NH1 + k0 + sl * 8];
        }
        __syncthreads();
        *(int4*)&Asm[arow * 72 + asl * 8] = ra;
        #pragma unroll
        for (int i = 0; i < 4; ++i) {
            int ch = t + i * 512;
            int row = ch >> 3, sl = ch & 7;
            *(int4*)&Bsm[row * 72 + sl * 8] = rbv[i];
        }
        __syncthreads();

        #pragma unroll
        for (int kk = 0; kk < 2; ++kk) {
            bf16x8 af[2], bfr[4];
            #pragma unroll
            for (int m = 0; m < 2; ++m)
                af[m] = *(const bf16x8*)&Asm[(wm * 32 + m * 16 + l16) * 72 + kk * 32 + g8];
            #pragma unroll
            for (int n = 0; n < 4; ++n)
                bfr[n] = *(const bf16x8*)&Bsm[(wn * 64 + n * 16 + l16) * 72 + kk * 32 + g8];
            #pragma unroll
            for (int m = 0; m < 2; ++m)
                #pragma unroll
                for (int n = 0; n < 4; ++n)
                    acc[m][n] = __builtin_amdgcn_mfma_f32_16x16x32_bf16(
                        af[m], bfr[n], acc[m][n], 0, 0, 0);
        }
    }

    float bv[4];
    #pragma unroll
    for (int n = 0; n < 4; ++n) bv[n] = b2[wn * 64 + n * 16 + l16];
    #pragma unroll
    for (int m = 0; m < 2; ++m)
        #pragma unroll
        for (int n = 0; n < 4; ++n)
            #pragma unroll
            for (int j = 0; j < 4; ++j) acc[m][n][j] += bv[n];

    #pragma unroll
    for (int m = 0; m < 2; ++m)
        #pragma unroll
        for (int j = 0; j < 4; ++j) {
            float p = 0.f, q = 0.f;
            #pragma unroll
            for (int n = 0; n < 4; ++n) {
                float v = acc[m][n][j];
                p += v; q += v * v;
            }
            #pragma unroll
            for (int off = 8; off; off >>= 1) {
                p += __shfl_xor(p, off);
                q += __shfl_xor(q, off);
            }
            if (l16 == 0) {
                red[wid][wm * 32 + m * 16 + g4 + j][0] = p;
                red[wid][wm * 32 + m * 16 + g4 + j][1] = q;
            }
        }
    __syncthreads();
    if (t < 64) {
        const int w0 = (t >> 5) * 4;
        float S = 0.f, S2 = 0.f;
        #pragma unroll
        for (int w = 0; w < 4; ++w) { S += red[w0 + w][t][0]; S2 += red[w0 + w][t][1]; }
        float mu  = S  * (1.f / NH2);
        float var = S2 * (1.f / NH2) - mu * mu;
        stats[t][0] = mu;
        stats[t][1] = rsqrtf(var + 1e-5f);
    }
    __syncthreads();

    float gv[4], ev[4];
    #pragma unroll
    for (int n = 0; n < 4; ++n) {
        int col = wn * 64 + n * 16 + l16;
        gv[n] = g2[col]; ev[n] = be2[col];
    }
    ushort* dst = h2 + (size_t)rb * NH2;
    #pragma unroll
    for (int m = 0; m < 2; ++m)
        #pragma unroll
        for (int j = 0; j < 4; ++j) {
            int row = wm * 32 + m * 16 + g4 + j;
            float mu = stats[row][0], rs = stats[row][1];
            #pragma unroll
            for (int n = 0; n < 4; ++n) {
                float val = fmaxf(fmaf((acc[m][n][j] - mu) * rs, gv[n], ev[n]), 0.f);
                dst[(size_t)row * NH2 + wn * 64 + n * 16 + l16] = f2bf(val);
            }
        }
}

// ---------------------------------------------------------------------------
// k3a (MFMA): W_flat(bf16) = h2 @ Wd + bd, packed into the SECOND half of each
// output row's fp32 slot (row*12288B + 6144B). Epilogue staged through LDS.
__global__ __launch_bounds__(256) void k_gemm_wd_mfma(
    const ushort* __restrict__ h2, const ushort* __restrict__ Wdt,
    const float* __restrict__ bd, ushort* __restrict__ outw)
{
    __shared__ ushort smem[2 * 128 * 72];   // Asm | Bsm; reused for C-stage
    ushort* Asm = smem;
    ushort* Bsm = smem + 128 * 72;

    const int t    = threadIdx.x;
    const int lane = t & 63;
    const int wid  = t >> 6;
    const int wm   = wid >> 1;
    const int wn   = wid & 1;
    const int l16  = lane & 15;
    const int g8   = (lane >> 4) * 8;
    const int g4   = (lane >> 4) * 4;

    const int rb = blockIdx.y * 128;
    const int cb = blockIdx.x * 128;

    f32x4 acc[4][4] = {};

    for (int ks = 0; ks < 4; ++ks) {
        const int k0 = ks * 64;
        int4 ra[4], rbv[4];
        #pragma unroll
        for (int i = 0; i < 4; ++i) {
            int ch  = t + i * 256;
            int row = ch >> 3;
            int sl  = ch & 7;
            ra[i]  = *(const int4*)&h2 [(size_t)(rb + row) * NH2 + k0 + sl * 8];
            rbv[i] = *(const int4*)&Wdt[(size_t)(cb + row) * NH2 + k0 + sl * 8];
        }
        __syncthreads();
        #pragma unroll
        for (int i = 0; i < 4; ++i) {
            int ch  = t + i * 256;
            int row = ch >> 3;
            int sl  = ch & 7;
            *(int4*)&Asm[row * 72 + sl * 8] = ra[i];
            *(int4*)&Bsm[row * 72 + sl * 8] = rbv[i];
        }
        __syncthreads();

        #pragma unroll
        for (int kk = 0; kk < 2; ++kk) {
            bf16x8 af[4], bfr[4];
            #pragma unroll
            for (int m = 0; m < 4; ++m)
                af[m] = *(const bf16x8*)&Asm[(wm * 64 + m * 16 + l16) * 72 + kk * 32 + g8];
            #pragma unroll
            for (int n = 0; n < 4; ++n)
                bfr[n] = *(const bf16x8*)&Bsm[(wn * 64 + n * 16 + l16) * 72 + kk * 32 + g8];
            #pragma unroll
            for (int m = 0; m < 4; ++m)
                #pragma unroll
                for (int n = 0; n < 4; ++n)
                    acc[m][n] = __builtin_amdgcn_mfma_f32_16x16x32_bf16(
                        af[m], bfr[n], acc[m][n], 0, 0, 0);
        }
    }

    float bv[4];
    #pragma unroll
    for (int n = 0; n < 4; ++n)
        bv[n] = bd[cb + wn * 64 + n * 16 + l16];

    __syncthreads();
    #pragma unroll
    for (int m = 0; m < 4; ++m)
        #pragma unroll
        for (int n = 0; n < 4; ++n)
            #pragma unroll
            for (int j = 0; j < 4; ++j)
                smem[(wm * 64 + m * 16 + g4 + j) * 128 + wn * 64 + n * 16 + l16] =
                    f2bf(acc[m][n][j] + bv[n]);
    __syncthreads();
    #pragma unroll
    for (int i = 0; i < 8; ++i) {
        int ch  = t + i * 256;
        int row = ch >> 4;
        int q   = ch & 15;
        *(int4*)&outw[(size_t)(rb + row) * 6144 + 3072 + cb + q * 8] =
            *(const int4*)&smem[row * 128 + q * 8];
    }
}

// ---------------------------------------------------------------------------
// k3b (MFMA, fused softmax): attn = softmax(h2 @ Wa + ba)
// Tile 64 x 768 (full N), BK=64, 4 K-steps. 512 thr = 8 waves (2m x 4n),
// wave tile 32 x 192 (2x12 frags). Wat pre-transposed bf16 (768 x 256).
// fp32 output staged through LDS in two 32-row passes for full-line stores.
__global__ __launch_bounds__(512) void k_attn_mfma(
    const ushort* __restrict__ h2, const ushort* __restrict__ Wat,
    const float* __restrict__ ba, float* __restrict__ attn)
{
    __shared__ ushort Asm[64 * 72];      //   9.2 KB
    __shared__ ushort Bsm[768 * 72];     // 110.6 KB (reused as f32 stage [32][776])
    __shared__ float red[8][64];
    __shared__ float stats[64];

    const int t    = threadIdx.x;
    const int lane = t & 63;
    const int wid  = t >> 6;
    const int wm   = wid >> 2;          // 0..1
    const int wn   = wid & 3;           // 0..3
    const int l16  = lane & 15;
    const int g8   = (lane >> 4) * 8;
    const int g4   = (lane >> 4) * 4;
    const int rb   = blockIdx.x * 64;

    const int arow = t >> 3, asl = t & 7;

    f32x4 acc[2][12] = {};

    for (int ks = 0; ks < 4; ++ks) {
        const int k0 = ks * 64;
        int4 ra = *(const int4*)&h2[(size_t)(rb + arow) * NH2 + k0 + asl * 8];
        int4 rbv[12];
        #pragma unroll
        for (int i = 0; i < 12; ++i) {
            int ch = t + i * 512;           // B: 6144 chunks, 12/thread
            int row = ch >> 3, sl = ch & 7;
            rbv[i] = *(const int4*)&Wat[(size_t)row * NH2 + k0 + sl * 8];
        }
        __syncthreads();
        *(int4*)&Asm[arow * 72 + asl * 8] = ra;
        #pragma unroll
        for (int i = 0; i < 12; ++i) {
            int ch = t + i * 512;
            int row = ch >> 3, sl = ch & 7;
            *(int4*)&Bsm[row * 72 + sl * 8] = rbv[i];
        }
        __syncthreads();

        #pragma unroll
        for (int kk = 0; kk < 2; ++kk) {
            bf16x8 af[2], bfr[12];
            #pragma unroll
            for (int m = 0; m < 2; ++m)
                af[m] = *(const bf16x8*)&Asm[(wm * 32 + m * 16 + l16) * 72 + kk * 32 + g8];
            #pragma unroll
            for (int n = 0; n < 12; ++n)
                bfr[n] = *(const bf16x8*)&Bsm[(wn * 192 + n * 16 + l16) * 72 + kk * 32 + g8];
            #pragma unroll
            for (int m = 0; m < 2; ++m)
                #pragma unroll
                for (int n = 0; n < 12; ++n)
                    acc[m][n] = __builtin_amdgcn_mfma_f32_16x16x32_bf16(
                        af[m], bfr[n], acc[m][n], 0, 0, 0);
        }
    }

    // bias
    float bb[12];
    #pragma unroll
    for (int n = 0; n < 12; ++n) bb[n] = ba[wn * 192 + n * 16 + l16];
    #pragma unroll
    for (int m = 0; m < 2; ++m)
        #pragma unroll
        for (int n = 0; n < 12; ++n)
            #pragma unroll
            for (int j = 0; j < 4; ++j) acc[m][n][j] += bb[n];

    // row max
    #pragma unroll
    for (int m = 0; m < 2; ++m)
        #pragma unroll
        for (int j = 0; j < 4; ++j) {
            float p = acc[m][0][j];
            #pragma unroll
            for (int n = 1; n < 12; ++n) p = fmaxf(p, acc[m][n][j]);
            #pragma unroll
            for (int off = 8; off; off >>= 1) p = fmaxf(p, __shfl_xor(p, off));
            if (l16 == 0) red[wid][wm * 32 + m * 16 + g4 + j] = p;
        }
    __syncthreads();
    if (t < 64) {
        const int w0 = (t >> 5) * 4;
        stats[t] = fmaxf(fmaxf(red[w0][t], red[w0 + 1][t]),
                         fmaxf(red[w0 + 2][t], red[w0 + 3][t]));
    }
    __syncthreads();
    // exp + row sum
    #pragma unroll
    for (int m = 0; m < 2; ++m)
        #pragma unroll
        for (int j = 0; j < 4; ++j) {
            float M = stats[wm * 32 + m * 16 + g4 + j];
            float s = 0.f;
            #pragma unroll
            for (int n = 0; n < 12; ++n) {
                acc[m][n][j] = __expf(acc[m][n][j] - M);
                s += acc[m][n][j];
            }
            #pragma unroll
            for (int off = 8; off; off >>= 1) s += __shfl_xor(s, off);
            if (l16 == 0) red[wid][wm * 32 + m * 16 + g4 + j] = s;
        }
    __syncthreads();
    if (t < 64) {
        const int w0 = (t >> 5) * 4;
        stats[t] = 1.f / (red[w0][t] + red[w0 + 1][t] + red[w0 + 2][t] + red[w0 + 3][t]);
    }
    __syncthreads();

    // staged fp32 output, two 32-row passes (stride 776 floats: conflict-free)
    float* stage = (float*)Bsm;
    #pragma unroll
    for (int h = 0; h < 2; ++h) {
        if (wm == h) {
            #pragma unroll
            for (int m = 0; m < 2; ++m)
                #pragma unroll
                for (int j = 0; j < 4; ++j) {
                    const int r = m * 16 + g4 + j;
                    const float inv = stats[h * 32 + r];
                    #pragma unroll
                    for (int n = 0; n < 12; ++n)
                        stage[r * 776 + wn * 192 + n * 16 + l16] = acc[m][n][j] * inv;
                }
        }
        __syncthreads();
        #pragma unroll
        for (int i = 0; i < 12; ++i) {
            int ch  = t + i * 512;          // 6144 chunks of 16 B
            int row = ch / 192;
            int q   = ch - row * 192;
            *(float4*)&attn[(size_t)(rb + h * 32 + row) * DD + q * 4] =
                *(const float4*)&stage[row * 776 + q * 4];
        }
        __syncthreads();
    }
}

// ---------------------------------------------------------------------------
// k4: per row: W = Wflat_bf16 * attn; modified Gram-Schmidt; normalize.
__global__ __launch_bounds__(256) void k_gs(float* __restrict__ out)
{
    const int wid  = threadIdx.x >> 6;
    const int lane = threadIdx.x & 63;
    const size_t row = (size_t)blockIdx.x * 4 + wid;

    float* Wf = out + row * (KK * DD);
    const ushort* wsrc = (const ushort*)out + row * 6144 + 3072;
    const float* at = out + (size_t)BSZ * (KK * DD) + row * DD;

    float a[12];
    #pragma unroll
    for (int k = 0; k < 3; ++k) {
        float4 av = *(const float4*)&at[lane * 4 + 256 * k];
        a[k * 4 + 0] = av.x; a[k * 4 + 1] = av.y;
        a[k * 4 + 2] = av.z; a[k * 4 + 3] = av.w;
    }
    float w[4][12];
    #pragma unroll
    for (int i = 0; i < 4; ++i) {
        #pragma unroll
        for (int k = 0; k < 3; ++k) {
            ushort4 uv = *(const ushort4*)&wsrc[i * DD + lane * 4 + 256 * k];
            w[i][k * 4 + 0] = bf2f(uv.x) * a[k * 4 + 0];
            w[i][k * 4 + 1] = bf2f(uv.y) * a[k * 4 + 1];
            w[i][k * 4 + 2] = bf2f(uv.z) * a[k * 4 + 2];
            w[i][k * 4 + 3] = bf2f(uv.w) * a[k * 4 + 3];
        }
    }
    #pragma unroll
    for (int i = 0; i < 4; ++i) {
        #pragma unroll
        for (int p = 0; p < i; ++p) {
            float s = 0.f;
            #pragma unroll
            for (int j = 0; j < 12; ++j) s = fmaf(w[i][j], w[p][j], s);
            #pragma unroll
            for (int off = 32; off; off >>= 1) s += __shfl_xor(s, off);
            #pragma unroll
            for (int j = 0; j < 12; ++j) w[i][j] = fmaf(-s, w[p][j], w[i][j]);
        }
        float n2 = 0.f;
        #pragma unroll
        for (int j = 0; j < 12; ++j) n2 = fmaf(w[i][j], w[i][j], n2);
        #pragma unroll
        for (int off = 32; off; off >>= 1) n2 += __shfl_xor(n2, off);
        float inv = 1.f / fmaxf(sqrtf(n2), 1e-12f);
        #pragma unroll
        for (int j = 0; j < 12; ++j) w[i][j] *= inv;
    }
    #pragma unroll
    for (int i = 0; i < 4; ++i) {
        #pragma unroll
        for (int k = 0; k < 3; ++k) {
            float4 wv;
            wv.x = w[i][k * 4 + 0]; wv.y = w[i][k * 4 + 1];
            wv.z = w[i][k * 4 + 2]; wv.w = w[i][k * 4 + 3];
            *(float4*)&Wf[i * DD + lane * 4 + 256 * k] = wv;
        }
    }
}

// ---------------------------------------------------------------------------
extern "C" void kernel_launch(void* const* d_in, const int* in_sizes, int n_in,
                              void* d_out, int out_size, void* d_ws, size_t ws_size,
                              hipStream_t stream)
{
    const float* emb = (const float*)d_in[0];
    const float* W1  = (const float*)d_in[1];
    const float* b1  = (const float*)d_in[2];
    const float* g1  = (const float*)d_in[3];
    const float* be1 = (const float*)d_in[4];
    const float* W2  = (const float*)d_in[5];
    const float* b2  = (const float*)d_in[6];
    const float* g2  = (const float*)d_in[7];
    const float* be2 = (const float*)d_in[8];
    const float* Wd  = (const float*)d_in[9];
    const float* bd  = (const float*)d_in[10];
    const float* Wa  = (const float*)d_in[11];
    const float* ba  = (const float*)d_in[12];

    float* out = (float*)d_out;
    ushort* h1  = (ushort*)d_ws;                 // B*512 bf16 = 16.8 MB
    ushort* h2  = h1 + (size_t)BSZ * NH1;        // B*256 bf16 =  8.4 MB
    ushort* Wdt = h2 + (size_t)BSZ * NH2;        // 3072*256 bf16 = 1.5 MB
    ushort* W1t = Wdt + (size_t)ND * NH2;        // 512*768 bf16 = 0.77 MB
    ushort* W2t = W1t + (size_t)NH1 * DD;        // 256*512 bf16 = 0.25 MB
    ushort* Wat = W2t + (size_t)NH2 * NH1;       // 768*256 bf16 = 0.39 MB
    float* attn = out + (size_t)BSZ * KK * DD;   // attn region, B*D

    hipLaunchKernelGGL(k_t_cvt, dim3(NH1 / 32, DD / 32), dim3(256), 0, stream,
                       W1, W1t, DD, NH1);        // W1 (768x512) -> W1t (512x768)
    hipLaunchKernelGGL(k_t_cvt, dim3(NH2 / 32, NH1 / 32), dim3(256), 0, stream,
                       W2, W2t, NH1, NH2);       // W2 (512x256) -> W2t (256x512)
    hipLaunchKernelGGL(k_t_cvt, dim3(ND / 32, NH2 / 32), dim3(256), 0, stream,
                       Wd, Wdt, NH2, ND);        // Wd (256x3072) -> Wdt (3072x256)
    hipLaunchKernelGGL(k_t_cvt, dim3(DD / 32, NH2 / 32), dim3(256), 0, stream,
                       Wa, Wat, NH2, DD);        // Wa (256x768) -> Wat (768x256)
    hipLaunchKernelGGL(k1_mfma, dim3(BSZ / 64), dim3(512), 0, stream,
                       emb, W1t, b1, g1, be1, h1);
    hipLaunchKernelGGL(k2_mfma, dim3(BSZ / 64), dim3(512), 0, stream,
                       h1, W2t, b2, g2, be2, h2);
    hipLaunchKernelGGL(k_gemm_wd_mfma, dim3(ND / 128, BSZ / 128), dim3(256), 0, stream,
                       h2, Wdt, bd, (ushort*)out);
    hipLaunchKernelGGL(k_attn_mfma, dim3(BSZ / 64), dim3(512), 0, stream,
                       h2, Wat, ba, attn);
    hipLaunchKernelGGL(k_gs, dim3(BSZ / 4), dim3(256), 0, stream, out);
}

// Round 7
// 338.163 us; speedup vs baseline: 2.3924x; 1.0401x over previous
//
#include <hip/hip_runtime.h>
#include <hip/hip_bf16.h>

#define BSZ 16384
#define DD  768
#define KK  4
#define NH1 512
#define NH2 256
#define ND  (KK * DD)   // 3072

typedef __bf16 bf16x8 __attribute__((ext_vector_type(8)));
typedef float  f32x4  __attribute__((ext_vector_type(4)));

static __device__ __forceinline__ float bf2f(ushort u) {
    union { unsigned int i; float f; } v; v.i = (unsigned int)u << 16; return v.f;
}
static __device__ __forceinline__ ushort f2bf(float f) {
    return __bfloat16_as_ushort(__float2bfloat16(f));
}

// ---------------------------------------------------------------------------
// k_t_cvt: src (R x C f32) -> dst (C x R bf16)  [generic transpose+convert]
__global__ __launch_bounds__(256) void k_t_cvt(
    const float* __restrict__ src, ushort* __restrict__ dst, int R, int C)
{
    __shared__ float tile[32][33];
    const int rb0 = blockIdx.y * 32;  // src row
    const int cb0 = blockIdx.x * 32;  // src col
    const int t = threadIdx.x;
    const int r = t >> 5, c = t & 31;
    #pragma unroll
    for (int i = 0; i < 4; ++i)
        tile[r + i * 8][c] = src[(size_t)(rb0 + r + i * 8) * C + cb0 + c];
    __syncthreads();
    #pragma unroll
    for (int i = 0; i < 4; ++i)
        dst[(size_t)(cb0 + r + i * 8) * R + rb0 + c] = f2bf(tile[c][r + i * 8]);
}

// ---------------------------------------------------------------------------
// k1_gemm: h1_raw = emb @ W1 + b1 (bf16), wd-kernel structure (4 blocks/CU).
// A = emb fp32 -> bf16 in-reg during staging. 128x128 tile, BK=64, 12 K-steps.
__global__ __launch_bounds__(256) void k1_gemm(
    const float* __restrict__ emb, const ushort* __restrict__ W1t,
    const float* __restrict__ b1, ushort* __restrict__ h1raw)
{
    __shared__ ushort smem[2 * 128 * 72];   // Asm | Bsm; reused for C-stage
    ushort* Asm = smem;
    ushort* Bsm = smem + 128 * 72;

    const int t    = threadIdx.x;
    const int lane = t & 63;
    const int wid  = t >> 6;
    const int wm   = wid >> 1;
    const int wn   = wid & 1;
    const int l16  = lane & 15;
    const int g8   = (lane >> 4) * 8;
    const int g4   = (lane >> 4) * 4;

    const int rb = blockIdx.y * 128;    // M tile
    const int cb = blockIdx.x * 128;    // N tile (over NH1=512)

    f32x4 acc[4][4] = {};

    for (int ks = 0; ks < 12; ++ks) {
        const int k0 = ks * 64;
        float4 ra0[4], ra1[4];
        int4 rbv[4];
        #pragma unroll
        for (int i = 0; i < 4; ++i) {
            int ch  = t + i * 256;          // 1024 chunks of 8 bf16 per matrix
            int row = ch >> 3;
            int sl  = ch & 7;
            ra0[i] = *(const float4*)&emb[(size_t)(rb + row) * DD + k0 + sl * 8];
            ra1[i] = *(const float4*)&emb[(size_t)(rb + row) * DD + k0 + sl * 8 + 4];
            rbv[i] = *(const int4*)&W1t[(size_t)(cb + row) * DD + k0 + sl * 8];
        }
        __syncthreads();   // all waves done reading previous tile
        #pragma unroll
        for (int i = 0; i < 4; ++i) {
            int ch  = t + i * 256;
            int row = ch >> 3;
            int sl  = ch & 7;
            ushort av[8];
            av[0] = f2bf(ra0[i].x); av[1] = f2bf(ra0[i].y);
            av[2] = f2bf(ra0[i].z); av[3] = f2bf(ra0[i].w);
            av[4] = f2bf(ra1[i].x); av[5] = f2bf(ra1[i].y);
            av[6] = f2bf(ra1[i].z); av[7] = f2bf(ra1[i].w);
            *(int4*)&Asm[row * 72 + sl * 8] = *(int4*)av;
            *(int4*)&Bsm[row * 72 + sl * 8] = rbv[i];
        }
        __syncthreads();   // staging visible

        #pragma unroll
        for (int kk = 0; kk < 2; ++kk) {
            bf16x8 af[4], bfr[4];
            #pragma unroll
            for (int m = 0; m < 4; ++m)
                af[m] = *(const bf16x8*)&Asm[(wm * 64 + m * 16 + l16) * 72 + kk * 32 + g8];
            #pragma unroll
            for (int n = 0; n < 4; ++n)
                bfr[n] = *(const bf16x8*)&Bsm[(wn * 64 + n * 16 + l16) * 72 + kk * 32 + g8];
            #pragma unroll
            for (int m = 0; m < 4; ++m)
                #pragma unroll
                for (int n = 0; n < 4; ++n)
                    acc[m][n] = __builtin_amdgcn_mfma_f32_16x16x32_bf16(
                        af[m], bfr[n], acc[m][n], 0, 0, 0);
        }
    }

    float bv[4];
    #pragma unroll
    for (int n = 0; n < 4; ++n)
        bv[n] = b1[cb + wn * 64 + n * 16 + l16];

    __syncthreads();
    #pragma unroll
    for (int m = 0; m < 4; ++m)
        #pragma unroll
        for (int n = 0; n < 4; ++n)
            #pragma unroll
            for (int j = 0; j < 4; ++j)
                smem[(wm * 64 + m * 16 + g4 + j) * 128 + wn * 64 + n * 16 + l16] =
                    f2bf(acc[m][n][j] + bv[n]);
    __syncthreads();
    #pragma unroll
    for (int i = 0; i < 8; ++i) {
        int ch  = t + i * 256;              // 2048 chunks of 16 B
        int row = ch >> 4;
        int q   = ch & 15;
        *(int4*)&h1raw[(size_t)(rb + row) * NH1 + cb + q * 8] =
            *(const int4*)&smem[row * 128 + q * 8];
    }
}

// ---------------------------------------------------------------------------
// k1_ln: in-place LN+relu over h1 rows (512 bf16). One wave per row.
__global__ __launch_bounds__(256) void k1_ln(
    ushort* h1, const float* __restrict__ g1, const float* __restrict__ be1)
{
    const int lane = threadIdx.x & 63;
    const int w    = threadIdx.x >> 6;
    const size_t row = (size_t)blockIdx.x * 4 + w;

    ushort* p = h1 + row * NH1 + lane * 8;
    ushort u[8];
    *(int4*)u = *(const int4*)p;
    float x[8];
    float s = 0.f, q = 0.f;
    #pragma unroll
    for (int j = 0; j < 8; ++j) {
        x[j] = bf2f(u[j]);
        s += x[j];
        q += x[j] * x[j];
    }
    #pragma unroll
    for (int off = 32; off; off >>= 1) {
        s += __shfl_xor(s, off);
        q += __shfl_xor(q, off);
    }
    const float mu  = s * (1.f / NH1);
    const float var = q * (1.f / NH1) - mu * mu;
    const float rs  = rsqrtf(var + 1e-5f);

    float gv[8], ev[8];
    *(float4*)&gv[0] = *(const float4*)&g1[lane * 8];
    *(float4*)&gv[4] = *(const float4*)&g1[lane * 8 + 4];
    *(float4*)&ev[0] = *(const float4*)&be1[lane * 8];
    *(float4*)&ev[4] = *(const float4*)&be1[lane * 8 + 4];
    #pragma unroll
    for (int j = 0; j < 8; ++j)
        u[j] = f2bf(fmaxf(fmaf((x[j] - mu) * rs, gv[j], ev[j]), 0.f));
    *(int4*)p = *(int4*)u;
}

// ---------------------------------------------------------------------------
// k2 (MFMA, fused LN+relu): h2 = relu(LN(h1 @ W2 + b2)) stored bf16
__global__ __launch_bounds__(512) void k2_mfma(
    const ushort* __restrict__ h1, const ushort* __restrict__ W2t,
    const float* __restrict__ b2, const float* __restrict__ g2,
    const float* __restrict__ be2, ushort* __restrict__ h2)
{
    __shared__ ushort Asm[64 * 72];     //  9.2 KB
    __shared__ ushort Bsm[256 * 72];    // 36.9 KB
    __shared__ float red[8][64][2];
    __shared__ float stats[64][2];

    const int t    = threadIdx.x;
    const int lane = t & 63;
    const int wid  = t >> 6;
    const int wm   = wid >> 2;          // 0..1
    const int wn   = wid & 3;           // 0..3
    const int l16  = lane & 15;
    const int g8   = (lane >> 4) * 8;
    const int g4   = (lane >> 4) * 4;
    const int rb   = blockIdx.x * 64;

    const int arow = t >> 3, asl = t & 7;   // A: 512 chunks, 1/thread

    f32x4 acc[2][4] = {};

    for (int ks = 0; ks < 8; ++ks) {
        const int k0 = ks * 64;
        int4 ra = *(const int4*)&h1[(size_t)(rb + arow) * NH1 + k0 + asl * 8];
        int4 rbv[4];
        #pragma unroll
        for (int i = 0; i < 4; ++i) {
            int ch = t + i * 512;           // B: 2048 chunks, 4/thread
            int row = ch >> 3, sl = ch & 7;
            rbv[i] = *(const int4*)&W2t[(size_t)row * NH1 + k0 + sl * 8];
        }
        __syncthreads();
        *(int4*)&Asm[arow * 72 + asl * 8] = ra;
        #pragma unroll
        for (int i = 0; i < 4; ++i) {
            int ch = t + i * 512;
            int row = ch >> 3, sl = ch & 7;
            *(int4*)&Bsm[row * 72 + sl * 8] = rbv[i];
        }
        __syncthreads();

        #pragma unroll
        for (int kk = 0; kk < 2; ++kk) {
            bf16x8 af[2], bfr[4];
            #pragma unroll
            for (int m = 0; m < 2; ++m)
                af[m] = *(const bf16x8*)&Asm[(wm * 32 + m * 16 + l16) * 72 + kk * 32 + g8];
            #pragma unroll
            for (int n = 0; n < 4; ++n)
                bfr[n] = *(const bf16x8*)&Bsm[(wn * 64 + n * 16 + l16) * 72 + kk * 32 + g8];
            #pragma unroll
            for (int m = 0; m < 2; ++m)
                #pragma unroll
                for (int n = 0; n < 4; ++n)
                    acc[m][n] = __builtin_amdgcn_mfma_f32_16x16x32_bf16(
                        af[m], bfr[n], acc[m][n], 0, 0, 0);
        }
    }

    float bv[4];
    #pragma unroll
    for (int n = 0; n < 4; ++n) bv[n] = b2[wn * 64 + n * 16 + l16];
    #pragma unroll
    for (int m = 0; m < 2; ++m)
        #pragma unroll
        for (int n = 0; n < 4; ++n)
            #pragma unroll
            for (int j = 0; j < 4; ++j) acc[m][n][j] += bv[n];

    #pragma unroll
    for (int m = 0; m < 2; ++m)
        #pragma unroll
        for (int j = 0; j < 4; ++j) {
            float p = 0.f, q = 0.f;
            #pragma unroll
            for (int n = 0; n < 4; ++n) {
                float v = acc[m][n][j];
                p += v; q += v * v;
            }
            #pragma unroll
            for (int off = 8; off; off >>= 1) {
                p += __shfl_xor(p, off);
                q += __shfl_xor(q, off);
            }
            if (l16 == 0) {
                red[wid][wm * 32 + m * 16 + g4 + j][0] = p;
                red[wid][wm * 32 + m * 16 + g4 + j][1] = q;
            }
        }
    __syncthreads();
    if (t < 64) {
        const int w0 = (t >> 5) * 4;
        float S = 0.f, S2 = 0.f;
        #pragma unroll
        for (int w = 0; w < 4; ++w) { S += red[w0 + w][t][0]; S2 += red[w0 + w][t][1]; }
        float mu  = S  * (1.f / NH2);
        float var = S2 * (1.f / NH2) - mu * mu;
        stats[t][0] = mu;
        stats[t][1] = rsqrtf(var + 1e-5f);
    }
    __syncthreads();

    float gv[4], ev[4];
    #pragma unroll
    for (int n = 0; n < 4; ++n) {
        int col = wn * 64 + n * 16 + l16;
        gv[n] = g2[col]; ev[n] = be2[col];
    }
    ushort* dst = h2 + (size_t)rb * NH2;
    #pragma unroll
    for (int m = 0; m < 2; ++m)
        #pragma unroll
        for (int j = 0; j < 4; ++j) {
            int row = wm * 32 + m * 16 + g4 + j;
            float mu = stats[row][0], rs = stats[row][1];
            #pragma unroll
            for (int n = 0; n < 4; ++n) {
                float val = fmaxf(fmaf((acc[m][n][j] - mu) * rs, gv[n], ev[n]), 0.f);
                dst[(size_t)row * NH2 + wn * 64 + n * 16 + l16] = f2bf(val);
            }
        }
}

// ---------------------------------------------------------------------------
// k3a (MFMA): W_flat(bf16) = h2 @ Wd + bd, packed into the SECOND half of each
// output row's fp32 slot (row*12288B + 6144B). Epilogue staged through LDS.
__global__ __launch_bounds__(256) void k_gemm_wd_mfma(
    const ushort* __restrict__ h2, const ushort* __restrict__ Wdt,
    const float* __restrict__ bd, ushort* __restrict__ outw)
{
    __shared__ ushort smem[2 * 128 * 72];   // Asm | Bsm; reused for C-stage
    ushort* Asm = smem;
    ushort* Bsm = smem + 128 * 72;

    const int t    = threadIdx.x;
    const int lane = t & 63;
    const int wid  = t >> 6;
    const int wm   = wid >> 1;
    const int wn   = wid & 1;
    const int l16  = lane & 15;
    const int g8   = (lane >> 4) * 8;
    const int g4   = (lane >> 4) * 4;

    const int rb = blockIdx.y * 128;
    const int cb = blockIdx.x * 128;

    f32x4 acc[4][4] = {};

    for (int ks = 0; ks < 4; ++ks) {
        const int k0 = ks * 64;
        int4 ra[4], rbv[4];
        #pragma unroll
        for (int i = 0; i < 4; ++i) {
            int ch  = t + i * 256;
            int row = ch >> 3;
            int sl  = ch & 7;
            ra[i]  = *(const int4*)&h2 [(size_t)(rb + row) * NH2 + k0 + sl * 8];
            rbv[i] = *(const int4*)&Wdt[(size_t)(cb + row) * NH2 + k0 + sl * 8];
        }
        __syncthreads();
        #pragma unroll
        for (int i = 0; i < 4; ++i) {
            int ch  = t + i * 256;
            int row = ch >> 3;
            int sl  = ch & 7;
            *(int4*)&Asm[row * 72 + sl * 8] = ra[i];
            *(int4*)&Bsm[row * 72 + sl * 8] = rbv[i];
        }
        __syncthreads();

        #pragma unroll
        for (int kk = 0; kk < 2; ++kk) {
            bf16x8 af[4], bfr[4];
            #pragma unroll
            for (int m = 0; m < 4; ++m)
                af[m] = *(const bf16x8*)&Asm[(wm * 64 + m * 16 + l16) * 72 + kk * 32 + g8];
            #pragma unroll
            for (int n = 0; n < 4; ++n)
                bfr[n] = *(const bf16x8*)&Bsm[(wn * 64 + n * 16 + l16) * 72 + kk * 32 + g8];
            #pragma unroll
            for (int m = 0; m < 4; ++m)
                #pragma unroll
                for (int n = 0; n < 4; ++n)
                    acc[m][n] = __builtin_amdgcn_mfma_f32_16x16x32_bf16(
                        af[m], bfr[n], acc[m][n], 0, 0, 0);
        }
    }

    float bv[4];
    #pragma unroll
    for (int n = 0; n < 4; ++n)
        bv[n] = bd[cb + wn * 64 + n * 16 + l16];

    __syncthreads();
    #pragma unroll
    for (int m = 0; m < 4; ++m)
        #pragma unroll
        for (int n = 0; n < 4; ++n)
            #pragma unroll
            for (int j = 0; j < 4; ++j)
                smem[(wm * 64 + m * 16 + g4 + j) * 128 + wn * 64 + n * 16 + l16] =
                    f2bf(acc[m][n][j] + bv[n]);
    __syncthreads();
    #pragma unroll
    for (int i = 0; i < 8; ++i) {
        int ch  = t + i * 256;
        int row = ch >> 4;
        int q   = ch & 15;
        *(int4*)&outw[(size_t)(rb + row) * 6144 + 3072 + cb + q * 8] =
            *(const int4*)&smem[row * 128 + q * 8];
    }
}

// ---------------------------------------------------------------------------
// k3b (MFMA, fused softmax): attn = softmax(h2 @ Wa + ba)
__global__ __launch_bounds__(512) void k_attn_mfma(
    const ushort* __restrict__ h2, const ushort* __restrict__ Wat,
    const float* __restrict__ ba, float* __restrict__ attn)
{
    __shared__ ushort Asm[64 * 72];      //   9.2 KB
    __shared__ ushort Bsm[768 * 72];     // 110.6 KB (reused as f32 stage [32][776])
    __shared__ float red[8][64];
    __shared__ float stats[64];

    const int t    = threadIdx.x;
    const int lane = t & 63;
    const int wid  = t >> 6;
    const int wm   = wid >> 2;          // 0..1
    const int wn   = wid & 3;           // 0..3
    const int l16  = lane & 15;
    const int g8   = (lane >> 4) * 8;
    const int g4   = (lane >> 4) * 4;
    const int rb   = blockIdx.x * 64;

    const int arow = t >> 3, asl = t & 7;

    f32x4 acc[2][12] = {};

    for (int ks = 0; ks < 4; ++ks) {
        const int k0 = ks * 64;
        int4 ra = *(const int4*)&h2[(size_t)(rb + arow) * NH2 + k0 + asl * 8];
        int4 rbv[12];
        #pragma unroll
        for (int i = 0; i < 12; ++i) {
            int ch = t + i * 512;           // B: 6144 chunks, 12/thread
            int row = ch >> 3, sl = ch & 7;
            rbv[i] = *(const int4*)&Wat[(size_t)row * NH2 + k0 + sl * 8];
        }
        __syncthreads();
        *(int4*)&Asm[arow * 72 + asl * 8] = ra;
        #pragma unroll
        for (int i = 0; i < 12; ++i) {
            int ch = t + i * 512;
            int row = ch >> 3, sl = ch & 7;
            *(int4*)&Bsm[row * 72 + sl * 8] = rbv[i];
        }
        __syncthreads();

        #pragma unroll
        for (int kk = 0; kk < 2; ++kk) {
            bf16x8 af[2], bfr[12];
            #pragma unroll
            for (int m = 0; m < 2; ++m)
                af[m] = *(const bf16x8*)&Asm[(wm * 32 + m * 16 + l16) * 72 + kk * 32 + g8];
            #pragma unroll
            for (int n = 0; n < 12; ++n)
                bfr[n] = *(const bf16x8*)&Bsm[(wn * 192 + n * 16 + l16) * 72 + kk * 32 + g8];
            #pragma unroll
            for (int m = 0; m < 2; ++m)
                #pragma unroll
                for (int n = 0; n < 12; ++n)
                    acc[m][n] = __builtin_amdgcn_mfma_f32_16x16x32_bf16(
                        af[m], bfr[n], acc[m][n], 0, 0, 0);
        }
    }

    // bias
    float bb[12];
    #pragma unroll
    for (int n = 0; n < 12; ++n) bb[n] = ba[wn * 192 + n * 16 + l16];
    #pragma unroll
    for (int m = 0; m < 2; ++m)
        #pragma unroll
        for (int n = 0; n < 12; ++n)
            #pragma unroll
            for (int j = 0; j < 4; ++j) acc[m][n][j] += bb[n];

    // row max
    #pragma unroll
    for (int m = 0; m < 2; ++m)
        #pragma unroll
        for (int j = 0; j < 4; ++j) {
            float p = acc[m][0][j];
            #pragma unroll
            for (int n = 1; n < 12; ++n) p = fmaxf(p, acc[m][n][j]);
            #pragma unroll
            for (int off = 8; off; off >>= 1) p = fmaxf(p, __shfl_xor(p, off));
            if (l16 == 0) red[wid][wm * 32 + m * 16 + g4 + j] = p;
        }
    __syncthreads();
    if (t < 64) {
        const int w0 = (t >> 5) * 4;
        stats[t] = fmaxf(fmaxf(red[w0][t], red[w0 + 1][t]),
                         fmaxf(red[w0 + 2][t], red[w0 + 3][t]));
    }
    __syncthreads();
    // exp + row sum
    #pragma unroll
    for (int m = 0; m < 2; ++m)
        #pragma unroll
        for (int j = 0; j < 4; ++j) {
            float M = stats[wm * 32 + m * 16 + g4 + j];
            float s = 0.f;
            #pragma unroll
            for (int n = 0; n < 12; ++n) {
                acc[m][n][j] = __expf(acc[m][n][j] - M);
                s += acc[m][n][j];
            }
            #pragma unroll
            for (int off = 8; off; off >>= 1) s += __shfl_xor(s, off);
            if (l16 == 0) red[wid][wm * 32 + m * 16 + g4 + j] = s;
        }
    __syncthreads();
    if (t < 64) {
        const int w0 = (t >> 5) * 4;
        stats[t] = 1.f / (red[w0][t] + red[w0 + 1][t] + red[w0 + 2][t] + red[w0 + 3][t]);
    }
    __syncthreads();

    // staged fp32 output, two 32-row passes (stride 776 floats: conflict-free)
    float* stage = (float*)Bsm;
    #pragma unroll
    for (int h = 0; h < 2; ++h) {
        if (wm == h) {
            #pragma unroll
            for (int m = 0; m < 2; ++m)
                #pragma unroll
                for (int j = 0; j < 4; ++j) {
                    const int r = m * 16 + g4 + j;
                    const float inv = stats[h * 32 + r];
                    #pragma unroll
                    for (int n = 0; n < 12; ++n)
                        stage[r * 776 + wn * 192 + n * 16 + l16] = acc[m][n][j] * inv;
                }
        }
        __syncthreads();
        #pragma unroll
        for (int i = 0; i < 12; ++i) {
            int ch  = t + i * 512;          // 6144 chunks of 16 B
            int row = ch / 192;
            int q   = ch - row * 192;
            *(float4*)&attn[(size_t)(rb + h * 32 + row) * DD + q * 4] =
                *(const float4*)&stage[row * 776 + q * 4];
        }
        __syncthreads();
    }
}

// ---------------------------------------------------------------------------
// k4: per row: W = Wflat_bf16 * attn; modified Gram-Schmidt; normalize.
__global__ __launch_bounds__(256) void k_gs(float* __restrict__ out)
{
    const int wid  = threadIdx.x >> 6;
    const int lane = threadIdx.x & 63;
    const size_t row = (size_t)blockIdx.x * 4 + wid;

    float* Wf = out + row * (KK * DD);
    const ushort* wsrc = (const ushort*)out + row * 6144 + 3072;
    const float* at = out + (size_t)BSZ * (KK * DD) + row * DD;

    float a[12];
    #pragma unroll
    for (int k = 0; k < 3; ++k) {
        float4 av = *(const float4*)&at[lane * 4 + 256 * k];
        a[k * 4 + 0] = av.x; a[k * 4 + 1] = av.y;
        a[k * 4 + 2] = av.z; a[k * 4 + 3] = av.w;
    }
    float w[4][12];
    #pragma unroll
    for (int i = 0; i < 4; ++i) {
        #pragma unroll
        for (int k = 0; k < 3; ++k) {
            ushort4 uv = *(const ushort4*)&wsrc[i * DD + lane * 4 + 256 * k];
            w[i][k * 4 + 0] = bf2f(uv.x) * a[k * 4 + 0];
            w[i][k * 4 + 1] = bf2f(uv.y) * a[k * 4 + 1];
            w[i][k * 4 + 2] = bf2f(uv.z) * a[k * 4 + 2];
            w[i][k * 4 + 3] = bf2f(uv.w) * a[k * 4 + 3];
        }
    }
    #pragma unroll
    for (int i = 0; i < 4; ++i) {
        #pragma unroll
        for (int p = 0; p < i; ++p) {
            float s = 0.f;
            #pragma unroll
            for (int j = 0; j < 12; ++j) s = fmaf(w[i][j], w[p][j], s);
            #pragma unroll
            for (int off = 32; off; off >>= 1) s += __shfl_xor(s, off);
            #pragma unroll
            for (int j = 0; j < 12; ++j) w[i][j] = fmaf(-s, w[p][j], w[i][j]);
        }
        float n2 = 0.f;
        #pragma unroll
        for (int j = 0; j < 12; ++j) n2 = fmaf(w[i][j], w[i][j], n2);
        #pragma unroll
        for (int off = 32; off; off >>= 1) n2 += __shfl_xor(n2, off);
        float inv = 1.f / fmaxf(sqrtf(n2), 1e-12f);
        #pragma unroll
        for (int j = 0; j < 12; ++j) w[i][j] *= inv;
    }
    #pragma unroll
    for (int i = 0; i < 4; ++i) {
        #pragma unroll
        for (int k = 0; k < 3; ++k) {
            float4 wv;
            wv.x = w[i][k * 4 + 0]; wv.y = w[i][k * 4 + 1];
            wv.z = w[i][k * 4 + 2]; wv.w = w[i][k * 4 + 3];
            *(float4*)&Wf[i * DD + lane * 4 + 256 * k] = wv;
        }
    }
}

// ---------------------------------------------------------------------------
extern "C" void kernel_launch(void* const* d_in, const int* in_sizes, int n_in,
                              void* d_out, int out_size, void* d_ws, size_t ws_size,
                              hipStream_t stream)
{
    const float* emb = (const float*)d_in[0];
    const float* W1  = (const float*)d_in[1];
    const float* b1  = (const float*)d_in[2];
    const float* g1  = (const float*)d_in[3];
    const float* be1 = (const float*)d_in[4];
    const float* W2  = (const float*)d_in[5];
    const float* b2  = (const float*)d_in[6];
    const float* g2  = (const float*)d_in[7];
    const float* be2 = (const float*)d_in[8];
    const float* Wd  = (const float*)d_in[9];
    const float* bd  = (const float*)d_in[10];
    const float* Wa  = (const float*)d_in[11];
    const float* ba  = (const float*)d_in[12];

    float* out = (float*)d_out;
    ushort* h1  = (ushort*)d_ws;                 // B*512 bf16 = 16.8 MB
    ushort* h2  = h1 + (size_t)BSZ * NH1;        // B*256 bf16 =  8.4 MB
    ushort* Wdt = h2 + (size_t)BSZ * NH2;        // 3072*256 bf16 = 1.5 MB
    ushort* W1t = Wdt + (size_t)ND * NH2;        // 512*768 bf16 = 0.77 MB
    ushort* W2t = W1t + (size_t)NH1 * DD;        // 256*512 bf16 = 0.25 MB
    ushort* Wat = W2t + (size_t)NH2 * NH1;       // 768*256 bf16 = 0.39 MB
    float* attn = out + (size_t)BSZ * KK * DD;   // attn region, B*D

    hipLaunchKernelGGL(k_t_cvt, dim3(NH1 / 32, DD / 32), dim3(256), 0, stream,
                       W1, W1t, DD, NH1);        // W1 (768x512) -> W1t (512x768)
    hipLaunchKernelGGL(k_t_cvt, dim3(NH2 / 32, NH1 / 32), dim3(256), 0, stream,
                       W2, W2t, NH1, NH2);       // W2 (512x256) -> W2t (256x512)
    hipLaunchKernelGGL(k_t_cvt, dim3(ND / 32, NH2 / 32), dim3(256), 0, stream,
                       Wd, Wdt, NH2, ND);        // Wd (256x3072) -> Wdt (3072x256)
    hipLaunchKernelGGL(k_t_cvt, dim3(DD / 32, NH2 / 32), dim3(256), 0, stream,
                       Wa, Wat, NH2, DD);        // Wa (256x768) -> Wat (768x256)
    hipLaunchKernelGGL(k1_gemm, dim3(NH1 / 128, BSZ / 128), dim3(256), 0, stream,
                       emb, W1t, b1, h1);
    hipLaunchKernelGGL(k1_ln, dim3(BSZ / 4), dim3(256), 0, stream,
                       h1, g1, be1);
    hipLaunchKernelGGL(k2_mfma, dim3(BSZ / 64), dim3(512), 0, stream,
                       h1, W2t, b2, g2, be2, h2);
    hipLaunchKernelGGL(k_gemm_wd_mfma, dim3(ND / 128, BSZ / 128), dim3(256), 0, stream,
                       h2, Wdt, bd, (ushort*)out);
    hipLaunchKernelGGL(k_attn_mfma, dim3(BSZ / 64), dim3(512), 0, stream,
                       h2, Wat, ba, attn);
    hipLaunchKernelGGL(k_gs, dim3(BSZ / 4), dim3(256), 0, stream, out);
}